// Round 11
// baseline (1026.130 us; speedup 1.0000x reference)
//
#include <hip/hip_runtime.h>
#include <hip/hip_bf16.h>
#include <cstdint>

#define HID 512
#define K1P 288   // feat K padded 272 -> 288 (9 x BK32)

typedef __attribute__((ext_vector_type(8))) short bf16x8;
typedef __attribute__((ext_vector_type(4))) float f32x4;

__device__ __forceinline__ short f2bf(float x) {
    __hip_bfloat16 h = __float2bfloat16(x);
    return *(short*)&h;
}
__device__ __forceinline__ float silu(float x) {
    return x * (1.0f / (1.0f + __expf(-x)));
}
__device__ __forceinline__ void gl_lds16(const void* src, void* dst) {
    __builtin_amdgcn_global_load_lds(
        (const __attribute__((address_space(1))) void*)src,
        (__attribute__((address_space(3))) void*)dst, 16, 0, 0);
}
// bijective XCD swizzle (m204)
__device__ __forceinline__ int xcd_swz(int bid, int nwg) {
    int q = nwg >> 3, r = nwg & 7;
    int xcd = bid & 7, i = bid >> 3;
    int base = (xcd < r) ? xcd * (q + 1) : r * (q + 1) + (xcd - r) * q;
    return base + i;
}

// ---------- 1) histogram ----------
__global__ __launch_bounds__(256) void hist_kernel(
    const int* __restrict__ idx, int* __restrict__ counts, int nEdges)
{
    int e = blockIdx.x * 256 + threadIdx.x;
    if (e < nEdges) atomicAdd(&counts[idx[e]], 1);
}

// ---------- 2) scan, pass 1 ----------
__global__ __launch_bounds__(1024) void scan1_kernel(
    const int* __restrict__ counts, int* __restrict__ starts,
    int* __restrict__ blockSum, int n)
{
    __shared__ int wsum[16];
    int t = threadIdx.x, lane = t & 63, wid = t >> 6;
    int i = blockIdx.x * 1024 + t;
    int v = (i < n) ? counts[i] : 0;
    int incl = v;
    #pragma unroll
    for (int off = 1; off < 64; off <<= 1) {
        int u = __shfl_up(incl, off);
        if (lane >= off) incl += u;
    }
    if (lane == 63) wsum[wid] = incl;
    __syncthreads();
    if (t < 16) {
        int s = wsum[t];
        #pragma unroll
        for (int off = 1; off < 16; off <<= 1) {
            int u = __shfl_up(s, off);
            if (t >= off) s += u;
        }
        wsum[t] = s;
    }
    __syncthreads();
    int woff = (wid == 0) ? 0 : wsum[wid - 1];
    if (i < n) starts[i] = woff + incl - v;
    if (t == 0) blockSum[blockIdx.x] = wsum[15];
}

// ---------- 2b) scan block sums ----------
__global__ __launch_bounds__(1024) void scan2_kernel(
    const int* __restrict__ blockSum, int* __restrict__ blockOff,
    int* __restrict__ starts, int nb, int n)
{
    __shared__ int arr[1024];
    int t = threadIdx.x;
    int v = (t < nb) ? blockSum[t] : 0;
    arr[t] = v;
    __syncthreads();
    #pragma unroll
    for (int off = 1; off < 1024; off <<= 1) {
        int x = (t >= off) ? arr[t - off] : 0;
        __syncthreads();
        arr[t] += x;
        __syncthreads();
    }
    if (t < nb) blockOff[t] = arr[t] - v;
    if (t == 0) starts[n] = arr[nb - 1];
}

// ---------- 2c) add offsets ----------
__global__ __launch_bounds__(1024) void scan3_kernel(
    int* __restrict__ starts, int* __restrict__ cursor,
    const int* __restrict__ blockOff, int n)
{
    int i = blockIdx.x * 1024 + threadIdx.x;
    if (i < n) {
        int s = starts[i] + blockOff[blockIdx.x];
        starts[i] = s;
        cursor[i] = s;
    }
}

// ---------- 3) scatter ----------
__global__ __launch_bounds__(256) void scatter_kernel(
    const float* __restrict__ R, const int* __restrict__ idx,
    int* __restrict__ cursor, float4* __restrict__ sorted, int nEdges)
{
    int e = blockIdx.x * 256 + threadIdx.x;
    if (e >= nEdges) return;
    int i = idx[e];
    int j = idx[nEdges + e];
    float rix = R[3*(size_t)i], riy = R[3*(size_t)i+1], riz = R[3*(size_t)i+2];
    float rjx = R[3*(size_t)j], rjy = R[3*(size_t)j+1], rjz = R[3*(size_t)j+2];
    float dx = rjx - rix, dy = rjy - riy, dz = rjz - riz;
    float r = sqrtf(dx*dx + dy*dy + dz*dz);
    float inv = 1.0f / (r + 1e-8f);
    int pos = atomicAdd(&cursor[i], 1);
    sorted[pos] = make_float4(r, dx*inv, dy*inv, dz*inv);
}

// ---------- 4) segmented reduce (unroll-4) ----------
__global__ __launch_bounds__(256) void accum_kernel(
    const float4* __restrict__ sorted, const int* __restrict__ starts,
    const float* __restrict__ centers, const float* __restrict__ width,
    float* __restrict__ M0M1, int nAtoms)
{
    int wv = threadIdx.x >> 6, lane = threadIdx.x & 63;
    int atom = blockIdx.x * 4 + wv;
    if (atom >= nAtoms) return;
    int s = starts[atom], e = starts[atom + 1];
    int k = lane >> 2, c = lane & 3;
    float ck = centers[k];
    float w = width[0];
    float inv2w2 = 1.0f / (2.0f * w * w);
    float acc = 0.0f;
    auto term = [&](float4 v) {
        float diff = v.x - ck;
        float b = __expf(-diff * diff * inv2w2);
        float comp = (c == 0) ? 1.0f : ((c == 1) ? v.y : ((c == 2) ? v.z : v.w));
        return b * comp;
    };
    int p = s;
    for (; p + 3 < e; p += 4) {
        float4 v0 = sorted[p];
        float4 v1 = sorted[p + 1];
        float4 v2 = sorted[p + 2];
        float4 v3 = sorted[p + 3];
        acc += term(v0); acc += term(v1); acc += term(v2); acc += term(v3);
    }
    for (; p < e; ++p) acc += term(sorted[p]);
    M0M1[(size_t)atom * 64 + lane] = acc;
}

// ---------- W -> bf16 transposed ----------
__global__ __launch_bounds__(256) void convW_kernel(
    const float* __restrict__ W, short* __restrict__ Wt, int K, int Kpad, int N)
{
    int n = blockIdx.x * 256 + threadIdx.x;
    int k = blockIdx.y;
    if (n >= N) return;
    float v = (k < K) ? W[(size_t)k * N + n] : 0.0f;
    Wt[(size_t)n * Kpad + k] = f2bf(v);
}

// ============ GEMM1: B-resident (W1 panel 72KB), feat-A in registers ============
// grid 256 blocks (4 col-slices x 64 row-groups), 512 thr, 16 rows/wave
__global__ __launch_bounds__(512, 2) void gemm1_bres(
    const float* __restrict__ M0M1, const short* __restrict__ W1t,
    const float* __restrict__ bias, short* __restrict__ C, int M, int T)
{
    __shared__ short Bp[4608 * 8];      // 72KB: 9 chunks x (4 k8 x 128 col) x 8 shorts
    __shared__ float MsT[8][64][16];    // 32KB: per-wave transposed M0M1 rows
    int t = threadIdx.x;
    int w = t >> 6, lane = t & 63;
    int li = lane & 15, lg = lane >> 4;
    int lin = xcd_swz(blockIdx.x, 256);
    int col0 = (lin & 3) * 128;
    int rg = lin >> 2;                  // 0..63

    // B panel: 4608 units, 9 gl_lds per thread, once
    #pragma unroll
    for (int i = 0; i < 9; ++i) {
        int cell = i * 512 + t;
        int c = cell >> 9, k8 = (cell >> 7) & 3, col = cell & 127;
        const short* src = W1t + (size_t)(col0 + col) * K1P + c * 32 + k8 * 8;
        gl_lds16(src, &Bp[(i * 512 + w * 64) * 8]);
    }
    asm volatile("s_waitcnt vmcnt(0)" ::: "memory");
    __syncthreads();

    float bv[8];
    #pragma unroll
    for (int n = 0; n < 8; ++n) bv[n] = bias[col0 + n * 16 + li];

    // preload first tile's row quarters
    float4 q0, q1, q2, q3;
    {
        int gr = rg * 128 + w * 16 + li; if (gr > M - 1) gr = M - 1;
        const float4* mrp = (const float4*)(M0M1 + (size_t)gr * 64 + lg * 16);
        q0 = mrp[0]; q1 = mrp[1]; q2 = mrp[2]; q3 = mrp[3];
    }

    for (int rt = rg; rt < T; rt += 64) {
        int row0w = rt * 128 + w * 16;
        // write my quarter transposed: MsT[w][lg*16 + j][li]
        MsT[w][lg*16+ 0][li] = q0.x; MsT[w][lg*16+ 1][li] = q0.y;
        MsT[w][lg*16+ 2][li] = q0.z; MsT[w][lg*16+ 3][li] = q0.w;
        MsT[w][lg*16+ 4][li] = q1.x; MsT[w][lg*16+ 5][li] = q1.y;
        MsT[w][lg*16+ 6][li] = q1.z; MsT[w][lg*16+ 7][li] = q1.w;
        MsT[w][lg*16+ 8][li] = q2.x; MsT[w][lg*16+ 9][li] = q2.y;
        MsT[w][lg*16+10][li] = q2.z; MsT[w][lg*16+11][li] = q2.w;
        MsT[w][lg*16+12][li] = q3.x; MsT[w][lg*16+13][li] = q3.y;
        MsT[w][lg*16+14][li] = q3.z; MsT[w][lg*16+15][li] = q3.w;
        asm volatile("s_waitcnt lgkmcnt(0)" ::: "memory");   // publish before cross-lane reads
        // prefetch next tile's quarters (hidden under this tile's compute)
        if (rt + 64 < T) {
            int gr = (rt + 64) * 128 + w * 16 + li; if (gr > M - 1) gr = M - 1;
            const float4* mrp = (const float4*)(M0M1 + (size_t)gr * 64 + lg * 16);
            q0 = mrp[0]; q1 = mrp[1]; q2 = mrp[2]; q3 = mrp[3];
        }
        // per-lane b-block registers: b = (lg&1)*8 + j, comps 1..3
        int bsel = (lg & 1) * 8;
        float brx[8], bry[8], brz[8];
        #pragma unroll
        for (int j = 0; j < 8; ++j) {
            brx[j] = MsT[w][4*(bsel+j)+1][li];
            bry[j] = MsT[w][4*(bsel+j)+2][li];
            brz[j] = MsT[w][4*(bsel+j)+3][li];
        }
        float m0r[8];
        if (lg < 2) {
            #pragma unroll
            for (int j = 0; j < 8; ++j) m0r[j] = MsT[w][4*(lg*8+j)][li];
        }
        // feat cell for step kt: my (k8=lg) 8 feats of row li
        auto featcell = [&](int kt) -> bf16x8 {
            int kbase = kt * 32 + lg * 8;
            bf16x8 v;
            if (kbase < 16) {
                #pragma unroll
                for (int j = 0; j < 8; ++j) v[j] = f2bf(m0r[j]);
            } else if (kbase < 272) {
                int a = (kbase - 16) >> 4;
                float ax = MsT[w][4*a+1][li], ay = MsT[w][4*a+2][li], az = MsT[w][4*a+3][li];
                #pragma unroll
                for (int j = 0; j < 8; ++j)
                    v[j] = f2bf(ax*brx[j] + ay*bry[j] + az*brz[j]);
            } else {
                #pragma unroll
                for (int j = 0; j < 8; ++j) v[j] = 0;
            }
            return v;
        };

        f32x4 acc[8] = {};
        bf16x8 acur = featcell(0);
        #pragma unroll
        for (int kt = 0; kt < 9; ++kt) {
            bf16x8 bfr[8];
            #pragma unroll
            for (int n = 0; n < 8; ++n)
                bfr[n] = *(const bf16x8*)&Bp[((kt*4 + lg)*128 + n*16 + li) * 8];
            bf16x8 anx = acur;
            if (kt < 8) anx = featcell(kt + 1);
            #pragma unroll
            for (int n = 0; n < 8; ++n)
                acc[n] = __builtin_amdgcn_mfma_f32_16x16x32_bf16(acur, bfr[n], acc[n], 0, 0, 0);
            acur = anx;
        }
        // epilogue: silu+bias -> h1
        #pragma unroll
        for (int r = 0; r < 4; ++r) {
            int row = row0w + lg*4 + r;
            if (row >= M) continue;
            size_t base = (size_t)row * HID + col0 + li;
            #pragma unroll
            for (int n = 0; n < 8; ++n) {
                float cx = acc[n][r] + bv[n];
                C[base + n*16] = f2bf(silu(cx));
            }
        }
    }
}

// ============ GEMM2: B-resident (W2 panel 128KB), A from global regs, fused energy ============
__global__ __launch_bounds__(512, 2) void gemm2_bres(
    const short* __restrict__ A, const short* __restrict__ W2t,
    const float* __restrict__ bias, const float* __restrict__ W3,
    const float* __restrict__ b3, const float* __restrict__ scale,
    const float* __restrict__ shift, const int* __restrict__ Z,
    float* __restrict__ out, int M, int T)
{
    __shared__ short Bp[8192 * 8];      // 128KB: 16 chunks x (4 k8 x 128 col) x 8 shorts
    int t = threadIdx.x;
    int w = t >> 6, lane = t & 63;
    int li = lane & 15, lg = lane >> 4;
    int lin = xcd_swz(blockIdx.x, 256);
    int col0 = (lin & 3) * 128;
    int rg = lin >> 2;

    #pragma unroll
    for (int i = 0; i < 16; ++i) {
        int cell = i * 512 + t;
        int c = cell >> 9, k8 = (cell >> 7) & 3, col = cell & 127;
        const short* src = W2t + (size_t)(col0 + col) * HID + c * 32 + k8 * 8;
        gl_lds16(src, &Bp[(i * 512 + w * 64) * 8]);
    }
    asm volatile("s_waitcnt vmcnt(0)" ::: "memory");
    __syncthreads();

    float bv[8], w3v[8];
    #pragma unroll
    for (int n = 0; n < 8; ++n) {
        int col = col0 + n * 16 + li;
        bv[n]  = bias[col];
        w3v[n] = W3[col];
    }
    float b30 = b3[0];
    float ew = 0.f;

    for (int rt = rg; rt < T; rt += 64) {
        int row0w = rt * 128 + w * 16;
        int gr = row0w + li; if (gr > M - 1) gr = M - 1;
        const short* arow = A + (size_t)gr * HID + lg * 8;
        bf16x8 areg[16];
        #pragma unroll
        for (int kt = 0; kt < 16; ++kt)
            areg[kt] = *(const bf16x8*)(arow + kt * 32);
        f32x4 acc[8] = {};
        #pragma unroll
        for (int kt = 0; kt < 16; ++kt) {
            bf16x8 bfr[8];
            #pragma unroll
            for (int n = 0; n < 8; ++n)
                bfr[n] = *(const bf16x8*)&Bp[((kt*4 + lg)*128 + n*16 + li) * 8];
            #pragma unroll
            for (int n = 0; n < 8; ++n)
                acc[n] = __builtin_amdgcn_mfma_f32_16x16x32_bf16(areg[kt], bfr[n], acc[n], 0, 0, 0);
        }
        // fused epilogue: silu + W3 dot + scale/shift, accumulate per-wave energy
        #pragma unroll
        for (int r = 0; r < 4; ++r) {
            float s = 0.f;
            #pragma unroll
            for (int n = 0; n < 8; ++n) {
                float cx = acc[n][r] + bv[n];
                s += silu(cx) * w3v[n];
            }
            s += __shfl_xor(s, 1);
            s += __shfl_xor(s, 2);
            s += __shfl_xor(s, 4);
            s += __shfl_xor(s, 8);
            int row = row0w + lg*4 + r;
            if (li == 0 && row < M) {
                int z = Z[row];
                float e = scale[z] * s;
                if (col0 == 0) e += scale[z] * b30 + shift[z];
                ew += e;
            }
        }
    }
    #pragma unroll
    for (int off = 32; off > 0; off >>= 1) ew += __shfl_down(ew, off);
    if (lane == 0) atomicAdd(out, ew);
}

extern "C" void kernel_launch(void* const* d_in, const int* in_sizes, int n_in,
                              void* d_out, int out_size, void* d_ws, size_t ws_size,
                              hipStream_t stream)
{
    const float* R       = (const float*)d_in[0];
    const int*   Z       = (const int*)  d_in[1];
    const int*   idx     = (const int*)  d_in[2];
    const float* centers = (const float*)d_in[5];
    const float* width   = (const float*)d_in[6];
    const float* W1      = (const float*)d_in[7];
    const float* b1      = (const float*)d_in[8];
    const float* W2      = (const float*)d_in[9];
    const float* b2      = (const float*)d_in[10];
    const float* W3      = (const float*)d_in[11];
    const float* b3      = (const float*)d_in[12];
    const float* scale   = (const float*)d_in[13];
    const float* shift   = (const float*)d_in[14];

    int nAtoms = in_sizes[0] / 3;
    int nEdges = in_sizes[2] / 2;

    size_t m0m1_b = (size_t)nAtoms * 64 * sizeof(float);   // 25.6 MB
    size_t h1_b   = (size_t)nAtoms * HID * 2;              // 102.4 MB
    size_t w1t_b  = (size_t)HID * K1P * 2;                 // 288 KB
    size_t w2t_b  = (size_t)HID * HID * 2;                 // 512 KB
    if (ws_size < m0m1_b + h1_b + w1t_b + w2t_b) return;

    char* ws = (char*)d_ws;
    float* M0M1 = (float*)ws;
    char*  regB = ws + m0m1_b;
    short* h1   = (short*)regB;
    short* W1t  = (short*)(ws + m0m1_b + h1_b);
    short* W2t  = W1t + (size_t)HID * K1P;

    int nb = (nAtoms + 1023) / 1024;
    size_t sorted_b = (size_t)nEdges * sizeof(float4);
    float4* sorted = (float4*)regB;
    int* counts   = (int*)(regB + sorted_b);
    int* starts   = counts + nAtoms;
    int* cursor   = starts + nAtoms + 1;
    int* blockSum = cursor + nAtoms;
    int* blockOff = blockSum + nb;
    if (sorted_b + (size_t)(3 * nAtoms + 1 + 2 * nb) * sizeof(int) > h1_b) return;

    float* out = (float*)d_out;

    hipMemsetAsync(counts, 0, (size_t)nAtoms * sizeof(int), stream);
    hipMemsetAsync(out, 0, sizeof(float), stream);

    convW_kernel<<<dim3(2, K1P), 256, 0, stream>>>(W1, W1t, 272, K1P, HID);
    convW_kernel<<<dim3(2, HID), 256, 0, stream>>>(W2, W2t, HID, HID, HID);

    int eb = (nEdges + 255) / 256;
    hist_kernel <<<eb, 256, 0, stream>>>(idx, counts, nEdges);
    scan1_kernel<<<nb, 1024, 0, stream>>>(counts, starts, blockSum, nAtoms);
    scan2_kernel<<<1, 1024, 0, stream>>>(blockSum, blockOff, starts, nb, nAtoms);
    scan3_kernel<<<nb, 1024, 0, stream>>>(starts, cursor, blockOff, nAtoms);
    scatter_kernel<<<eb, 256, 0, stream>>>(R, idx, cursor, sorted, nEdges);
    accum_kernel<<<(nAtoms + 3) / 4, 256, 0, stream>>>(sorted, starts, centers, width, M0M1, nAtoms);

    int T = (nAtoms + 127) / 128;   // 782 row-tiles
    gemm1_bres<<<256, 512, 0, stream>>>(M0M1, W1t, b1, h1, nAtoms, T);
    gemm2_bres<<<256, 512, 0, stream>>>(h1, W2t, b2, W3, b3, scale, shift, Z, out, nAtoms, T);
}

// Round 12
// 1020.746 us; speedup vs baseline: 1.0053x; 1.0053x over previous
//
#include <hip/hip_runtime.h>
#include <hip/hip_bf16.h>
#include <cstdint>

#define HID 512
#define K1P 288   // feat K padded 272 -> 288 (9 x BK32)

typedef __attribute__((ext_vector_type(8))) short bf16x8;
typedef __attribute__((ext_vector_type(4))) float f32x4;

__device__ __forceinline__ short f2bf(float x) {
    __hip_bfloat16 h = __float2bfloat16(x);
    return *(short*)&h;
}
__device__ __forceinline__ float silu(float x) {
    return x * (1.0f / (1.0f + __expf(-x)));
}
__device__ __forceinline__ void gl_lds16(const void* src, void* dst) {
    __builtin_amdgcn_global_load_lds(
        (const __attribute__((address_space(1))) void*)src,
        (__attribute__((address_space(3))) void*)dst, 16, 0, 0);
}
// bijective XCD swizzle (m204)
__device__ __forceinline__ int xcd_swz(int bid, int nwg) {
    int q = nwg >> 3, r = nwg & 7;
    int xcd = bid & 7, i = bid >> 3;
    int base = (xcd < r) ? xcd * (q + 1) : r * (q + 1) + (xcd - r) * q;
    return base + i;
}

// ---------- 1) histogram ----------
__global__ __launch_bounds__(256) void hist_kernel(
    const int* __restrict__ idx, int* __restrict__ counts, int nEdges)
{
    int e = blockIdx.x * 256 + threadIdx.x;
    if (e < nEdges) atomicAdd(&counts[idx[e]], 1);
}

// ---------- 2) scan, pass 1 ----------
__global__ __launch_bounds__(1024) void scan1_kernel(
    const int* __restrict__ counts, int* __restrict__ starts,
    int* __restrict__ blockSum, int n)
{
    __shared__ int wsum[16];
    int t = threadIdx.x, lane = t & 63, wid = t >> 6;
    int i = blockIdx.x * 1024 + t;
    int v = (i < n) ? counts[i] : 0;
    int incl = v;
    #pragma unroll
    for (int off = 1; off < 64; off <<= 1) {
        int u = __shfl_up(incl, off);
        if (lane >= off) incl += u;
    }
    if (lane == 63) wsum[wid] = incl;
    __syncthreads();
    if (t < 16) {
        int s = wsum[t];
        #pragma unroll
        for (int off = 1; off < 16; off <<= 1) {
            int u = __shfl_up(s, off);
            if (t >= off) s += u;
        }
        wsum[t] = s;
    }
    __syncthreads();
    int woff = (wid == 0) ? 0 : wsum[wid - 1];
    if (i < n) starts[i] = woff + incl - v;
    if (t == 0) blockSum[blockIdx.x] = wsum[15];
}

// ---------- 2b) scan block sums ----------
__global__ __launch_bounds__(1024) void scan2_kernel(
    const int* __restrict__ blockSum, int* __restrict__ blockOff,
    int* __restrict__ starts, int nb, int n)
{
    __shared__ int arr[1024];
    int t = threadIdx.x;
    int v = (t < nb) ? blockSum[t] : 0;
    arr[t] = v;
    __syncthreads();
    #pragma unroll
    for (int off = 1; off < 1024; off <<= 1) {
        int x = (t >= off) ? arr[t - off] : 0;
        __syncthreads();
        arr[t] += x;
        __syncthreads();
    }
    if (t < nb) blockOff[t] = arr[t] - v;
    if (t == 0) starts[n] = arr[nb - 1];
}

// ---------- 2c) add offsets ----------
__global__ __launch_bounds__(1024) void scan3_kernel(
    int* __restrict__ starts, int* __restrict__ cursor,
    const int* __restrict__ blockOff, int n)
{
    int i = blockIdx.x * 1024 + threadIdx.x;
    if (i < n) {
        int s = starts[i] + blockOff[blockIdx.x];
        starts[i] = s;
        cursor[i] = s;
    }
}

// ---------- 3) scatter ----------
__global__ __launch_bounds__(256) void scatter_kernel(
    const float* __restrict__ R, const int* __restrict__ idx,
    int* __restrict__ cursor, float4* __restrict__ sorted, int nEdges)
{
    int e = blockIdx.x * 256 + threadIdx.x;
    if (e >= nEdges) return;
    int i = idx[e];
    int j = idx[nEdges + e];
    float rix = R[3*(size_t)i], riy = R[3*(size_t)i+1], riz = R[3*(size_t)i+2];
    float rjx = R[3*(size_t)j], rjy = R[3*(size_t)j+1], rjz = R[3*(size_t)j+2];
    float dx = rjx - rix, dy = rjy - riy, dz = rjz - riz;
    float r = sqrtf(dx*dx + dy*dy + dz*dz);
    float inv = 1.0f / (r + 1e-8f);
    int pos = atomicAdd(&cursor[i], 1);
    sorted[pos] = make_float4(r, dx*inv, dy*inv, dz*inv);
}

// ---------- 4) segmented reduce (unroll-4) ----------
__global__ __launch_bounds__(256) void accum_kernel(
    const float4* __restrict__ sorted, const int* __restrict__ starts,
    const float* __restrict__ centers, const float* __restrict__ width,
    float* __restrict__ M0M1, int nAtoms)
{
    int wv = threadIdx.x >> 6, lane = threadIdx.x & 63;
    int atom = blockIdx.x * 4 + wv;
    if (atom >= nAtoms) return;
    int s = starts[atom], e = starts[atom + 1];
    int k = lane >> 2, c = lane & 3;
    float ck = centers[k];
    float w = width[0];
    float inv2w2 = 1.0f / (2.0f * w * w);
    float acc = 0.0f;
    auto term = [&](float4 v) {
        float diff = v.x - ck;
        float b = __expf(-diff * diff * inv2w2);
        float comp = (c == 0) ? 1.0f : ((c == 1) ? v.y : ((c == 2) ? v.z : v.w));
        return b * comp;
    };
    int p = s;
    for (; p + 3 < e; p += 4) {
        float4 v0 = sorted[p];
        float4 v1 = sorted[p + 1];
        float4 v2 = sorted[p + 2];
        float4 v3 = sorted[p + 3];
        acc += term(v0); acc += term(v1); acc += term(v2); acc += term(v3);
    }
    for (; p < e; ++p) acc += term(sorted[p]);
    M0M1[(size_t)atom * 64 + lane] = acc;
}

// ---------- W -> bf16 transposed ----------
__global__ __launch_bounds__(256) void convW_kernel(
    const float* __restrict__ W, short* __restrict__ Wt, int K, int Kpad, int N)
{
    int n = blockIdx.x * 256 + threadIdx.x;
    int k = blockIdx.y;
    if (n >= N) return;
    float v = (k < K) ? W[(size_t)k * N + n] : 0.0f;
    Wt[(size_t)n * Kpad + k] = f2bf(v);
}

// ============ GEMM1: B-resident (W1 panel 72KB), feat-A in registers ============
// grid 256 blocks (4 col-slices x 64 row-groups), 512 thr, 16 rows/wave
// NOTE: 2nd launch_bounds arg = min BLOCKS/CU (CUDA semantics). (512,2) capped
// VGPR at 128 -> areg spill -> R11's 1.13GB phantom FETCH. (512,1) -> 256 cap.
__global__ __launch_bounds__(512, 1) void gemm1_bres(
    const float* __restrict__ M0M1, const short* __restrict__ W1t,
    const float* __restrict__ bias, short* __restrict__ C, int M, int T)
{
    __shared__ short Bp[4608 * 8];      // 72KB: 9 chunks x (4 k8 x 128 col) x 8 shorts
    __shared__ float MsT[8][64][16];    // 32KB: per-wave transposed M0M1 rows
    int t = threadIdx.x;
    int w = t >> 6, lane = t & 63;
    int li = lane & 15, lg = lane >> 4;
    int lin = xcd_swz(blockIdx.x, 256);
    int col0 = (lin & 3) * 128;
    int rg = lin >> 2;                  // 0..63

    // B panel: 4608 units, 9 gl_lds per thread, once
    #pragma unroll
    for (int i = 0; i < 9; ++i) {
        int cell = i * 512 + t;
        int c = cell >> 9, k8 = (cell >> 7) & 3, col = cell & 127;
        const short* src = W1t + (size_t)(col0 + col) * K1P + c * 32 + k8 * 8;
        gl_lds16(src, &Bp[(i * 512 + w * 64) * 8]);
    }
    asm volatile("s_waitcnt vmcnt(0)" ::: "memory");
    __syncthreads();

    float bv[8];
    #pragma unroll
    for (int n = 0; n < 8; ++n) bv[n] = bias[col0 + n * 16 + li];

    // preload first tile's row quarters
    float4 q0, q1, q2, q3;
    {
        int gr = rg * 128 + w * 16 + li; if (gr > M - 1) gr = M - 1;
        const float4* mrp = (const float4*)(M0M1 + (size_t)gr * 64 + lg * 16);
        q0 = mrp[0]; q1 = mrp[1]; q2 = mrp[2]; q3 = mrp[3];
    }

    for (int rt = rg; rt < T; rt += 64) {
        int row0w = rt * 128 + w * 16;
        // write my quarter transposed: MsT[w][lg*16 + j][li]
        MsT[w][lg*16+ 0][li] = q0.x; MsT[w][lg*16+ 1][li] = q0.y;
        MsT[w][lg*16+ 2][li] = q0.z; MsT[w][lg*16+ 3][li] = q0.w;
        MsT[w][lg*16+ 4][li] = q1.x; MsT[w][lg*16+ 5][li] = q1.y;
        MsT[w][lg*16+ 6][li] = q1.z; MsT[w][lg*16+ 7][li] = q1.w;
        MsT[w][lg*16+ 8][li] = q2.x; MsT[w][lg*16+ 9][li] = q2.y;
        MsT[w][lg*16+10][li] = q2.z; MsT[w][lg*16+11][li] = q2.w;
        MsT[w][lg*16+12][li] = q3.x; MsT[w][lg*16+13][li] = q3.y;
        MsT[w][lg*16+14][li] = q3.z; MsT[w][lg*16+15][li] = q3.w;
        asm volatile("s_waitcnt lgkmcnt(0)" ::: "memory");   // wave-internal publish
        // prefetch next tile's quarters (hidden under this tile's compute)
        if (rt + 64 < T) {
            int gr = (rt + 64) * 128 + w * 16 + li; if (gr > M - 1) gr = M - 1;
            const float4* mrp = (const float4*)(M0M1 + (size_t)gr * 64 + lg * 16);
            q0 = mrp[0]; q1 = mrp[1]; q2 = mrp[2]; q3 = mrp[3];
        }
        // per-lane b-block registers: b = (lg&1)*8 + j, comps 1..3
        int bsel = (lg & 1) * 8;
        float brx[8], bry[8], brz[8];
        #pragma unroll
        for (int j = 0; j < 8; ++j) {
            brx[j] = MsT[w][4*(bsel+j)+1][li];
            bry[j] = MsT[w][4*(bsel+j)+2][li];
            brz[j] = MsT[w][4*(bsel+j)+3][li];
        }
        float m0r[8];
        if (lg < 2) {
            #pragma unroll
            for (int j = 0; j < 8; ++j) m0r[j] = MsT[w][4*(lg*8+j)][li];
        }
        // feat cell for step kt: my (k8=lg) 8 feats of row li
        auto featcell = [&](int kt) -> bf16x8 {
            int kbase = kt * 32 + lg * 8;
            bf16x8 v;
            if (kbase < 16) {
                #pragma unroll
                for (int j = 0; j < 8; ++j) v[j] = f2bf(m0r[j]);
            } else if (kbase < 272) {
                int a = (kbase - 16) >> 4;
                float ax = MsT[w][4*a+1][li], ay = MsT[w][4*a+2][li], az = MsT[w][4*a+3][li];
                #pragma unroll
                for (int j = 0; j < 8; ++j)
                    v[j] = f2bf(ax*brx[j] + ay*bry[j] + az*brz[j]);
            } else {
                #pragma unroll
                for (int j = 0; j < 8; ++j) v[j] = 0;
            }
            return v;
        };

        f32x4 acc[8] = {};
        bf16x8 acur = featcell(0);
        #pragma unroll
        for (int kt = 0; kt < 9; ++kt) {
            bf16x8 bfr[8];
            #pragma unroll
            for (int n = 0; n < 8; ++n)
                bfr[n] = *(const bf16x8*)&Bp[((kt*4 + lg)*128 + n*16 + li) * 8];
            bf16x8 anx = acur;
            if (kt < 8) anx = featcell(kt + 1);
            #pragma unroll
            for (int n = 0; n < 8; ++n)
                acc[n] = __builtin_amdgcn_mfma_f32_16x16x32_bf16(acur, bfr[n], acc[n], 0, 0, 0);
            acur = anx;
        }
        // epilogue: silu+bias -> h1
        #pragma unroll
        for (int r = 0; r < 4; ++r) {
            int row = row0w + lg*4 + r;
            if (row >= M) continue;
            size_t base = (size_t)row * HID + col0 + li;
            #pragma unroll
            for (int n = 0; n < 8; ++n) {
                float cx = acc[n][r] + bv[n];
                C[base + n*16] = f2bf(silu(cx));
            }
        }
    }
}

// ============ GEMM2: B-resident (W2 panel 128KB), A from global regs, fused energy ============
__global__ __launch_bounds__(512, 1) void gemm2_bres(
    const short* __restrict__ A, const short* __restrict__ W2t,
    const float* __restrict__ bias, const float* __restrict__ W3,
    const float* __restrict__ b3, const float* __restrict__ scale,
    const float* __restrict__ shift, const int* __restrict__ Z,
    float* __restrict__ out, int M, int T)
{
    __shared__ short Bp[8192 * 8];      // 128KB: 16 chunks x (4 k8 x 128 col) x 8 shorts
    int t = threadIdx.x;
    int w = t >> 6, lane = t & 63;
    int li = lane & 15, lg = lane >> 4;
    int lin = xcd_swz(blockIdx.x, 256);
    int col0 = (lin & 3) * 128;
    int rg = lin >> 2;

    #pragma unroll
    for (int i = 0; i < 16; ++i) {
        int cell = i * 512 + t;
        int c = cell >> 9, k8 = (cell >> 7) & 3, col = cell & 127;
        const short* src = W2t + (size_t)(col0 + col) * HID + c * 32 + k8 * 8;
        gl_lds16(src, &Bp[(i * 512 + w * 64) * 8]);
    }
    asm volatile("s_waitcnt vmcnt(0)" ::: "memory");
    __syncthreads();

    float bv[8], w3v[8];
    #pragma unroll
    for (int n = 0; n < 8; ++n) {
        int col = col0 + n * 16 + li;
        bv[n]  = bias[col];
        w3v[n] = W3[col];
    }
    float b30 = b3[0];
    float ew = 0.f;

    for (int rt = rg; rt < T; rt += 64) {
        int row0w = rt * 128 + w * 16;
        int gr = row0w + li; if (gr > M - 1) gr = M - 1;
        const short* arow = A + (size_t)gr * HID + lg * 8;
        bf16x8 areg[16];
        #pragma unroll
        for (int kt = 0; kt < 16; ++kt)
            areg[kt] = *(const bf16x8*)(arow + kt * 32);
        f32x4 acc[8] = {};
        #pragma unroll
        for (int kt = 0; kt < 16; ++kt) {
            bf16x8 bfr[8];
            #pragma unroll
            for (int n = 0; n < 8; ++n)
                bfr[n] = *(const bf16x8*)&Bp[((kt*4 + lg)*128 + n*16 + li) * 8];
            #pragma unroll
            for (int n = 0; n < 8; ++n)
                acc[n] = __builtin_amdgcn_mfma_f32_16x16x32_bf16(areg[kt], bfr[n], acc[n], 0, 0, 0);
        }
        // fused epilogue: silu + W3 dot + scale/shift, accumulate per-wave energy
        #pragma unroll
        for (int r = 0; r < 4; ++r) {
            float s = 0.f;
            #pragma unroll
            for (int n = 0; n < 8; ++n) {
                float cx = acc[n][r] + bv[n];
                s += silu(cx) * w3v[n];
            }
            s += __shfl_xor(s, 1);
            s += __shfl_xor(s, 2);
            s += __shfl_xor(s, 4);
            s += __shfl_xor(s, 8);
            int row = row0w + lg*4 + r;
            if (li == 0 && row < M) {
                int z = Z[row];
                float e = scale[z] * s;
                if (col0 == 0) e += scale[z] * b30 + shift[z];
                ew += e;
            }
        }
    }
    #pragma unroll
    for (int off = 32; off > 0; off >>= 1) ew += __shfl_down(ew, off);
    if (lane == 0) atomicAdd(out, ew);
}

extern "C" void kernel_launch(void* const* d_in, const int* in_sizes, int n_in,
                              void* d_out, int out_size, void* d_ws, size_t ws_size,
                              hipStream_t stream)
{
    const float* R       = (const float*)d_in[0];
    const int*   Z       = (const int*)  d_in[1];
    const int*   idx     = (const int*)  d_in[2];
    const float* centers = (const float*)d_in[5];
    const float* width   = (const float*)d_in[6];
    const float* W1      = (const float*)d_in[7];
    const float* b1      = (const float*)d_in[8];
    const float* W2      = (const float*)d_in[9];
    const float* b2      = (const float*)d_in[10];
    const float* W3      = (const float*)d_in[11];
    const float* b3      = (const float*)d_in[12];
    const float* scale   = (const float*)d_in[13];
    const float* shift   = (const float*)d_in[14];

    int nAtoms = in_sizes[0] / 3;
    int nEdges = in_sizes[2] / 2;

    size_t m0m1_b = (size_t)nAtoms * 64 * sizeof(float);   // 25.6 MB
    size_t h1_b   = (size_t)nAtoms * HID * 2;              // 102.4 MB
    size_t w1t_b  = (size_t)HID * K1P * 2;                 // 288 KB
    size_t w2t_b  = (size_t)HID * HID * 2;                 // 512 KB
    if (ws_size < m0m1_b + h1_b + w1t_b + w2t_b) return;

    char* ws = (char*)d_ws;
    float* M0M1 = (float*)ws;
    char*  regB = ws + m0m1_b;
    short* h1   = (short*)regB;
    short* W1t  = (short*)(ws + m0m1_b + h1_b);
    short* W2t  = W1t + (size_t)HID * K1P;

    int nb = (nAtoms + 1023) / 1024;
    size_t sorted_b = (size_t)nEdges * sizeof(float4);
    float4* sorted = (float4*)regB;
    int* counts   = (int*)(regB + sorted_b);
    int* starts   = counts + nAtoms;
    int* cursor   = starts + nAtoms + 1;
    int* blockSum = cursor + nAtoms;
    int* blockOff = blockSum + nb;
    if (sorted_b + (size_t)(3 * nAtoms + 1 + 2 * nb) * sizeof(int) > h1_b) return;

    float* out = (float*)d_out;

    hipMemsetAsync(counts, 0, (size_t)nAtoms * sizeof(int), stream);
    hipMemsetAsync(out, 0, sizeof(float), stream);

    convW_kernel<<<dim3(2, K1P), 256, 0, stream>>>(W1, W1t, 272, K1P, HID);
    convW_kernel<<<dim3(2, HID), 256, 0, stream>>>(W2, W2t, HID, HID, HID);

    int eb = (nEdges + 255) / 256;
    hist_kernel <<<eb, 256, 0, stream>>>(idx, counts, nEdges);
    scan1_kernel<<<nb, 1024, 0, stream>>>(counts, starts, blockSum, nAtoms);
    scan2_kernel<<<1, 1024, 0, stream>>>(blockSum, blockOff, starts, nb, nAtoms);
    scan3_kernel<<<nb, 1024, 0, stream>>>(starts, cursor, blockOff, nAtoms);
    scatter_kernel<<<eb, 256, 0, stream>>>(R, idx, cursor, sorted, nEdges);
    accum_kernel<<<(nAtoms + 3) / 4, 256, 0, stream>>>(sorted, starts, centers, width, M0M1, nAtoms);

    int T = (nAtoms + 127) / 128;   // 782 row-tiles
    gemm1_bres<<<256, 512, 0, stream>>>(M0M1, W1t, b1, h1, nAtoms, T);
    gemm2_bres<<<256, 512, 0, stream>>>(h1, W2t, b2, W3, b3, scale, shift, Z, out, nAtoms, T);
}

// Round 13
// 873.269 us; speedup vs baseline: 1.1750x; 1.1689x over previous
//
#include <hip/hip_runtime.h>
#include <hip/hip_bf16.h>
#include <cstdint>

#define HID 512
#define K1P 288   // feat K padded 272 -> 288 (9 x BK32)

typedef __attribute__((ext_vector_type(8))) short bf16x8;
typedef __attribute__((ext_vector_type(4))) float f32x4;

__device__ __forceinline__ short f2bf(float x) {
    __hip_bfloat16 h = __float2bfloat16(x);
    return *(short*)&h;
}
__device__ __forceinline__ float silu(float x) {
    return x * (1.0f / (1.0f + __expf(-x)));
}
__device__ __forceinline__ void gl_lds16(const void* src, void* dst) {
    __builtin_amdgcn_global_load_lds(
        (const __attribute__((address_space(1))) void*)src,
        (__attribute__((address_space(3))) void*)dst, 16, 0, 0);
}
// bijective XCD swizzle (m204)
__device__ __forceinline__ int xcd_swz(int bid, int nwg) {
    int q = nwg >> 3, r = nwg & 7;
    int xcd = bid & 7, i = bid >> 3;
    int base = (xcd < r) ? xcd * (q + 1) : r * (q + 1) + (xcd - r) * q;
    return base + i;
}

// ---------- 1) histogram ----------
__global__ __launch_bounds__(256) void hist_kernel(
    const int* __restrict__ idx, int* __restrict__ counts, int nEdges)
{
    int e = blockIdx.x * 256 + threadIdx.x;
    if (e < nEdges) atomicAdd(&counts[idx[e]], 1);
}

// ---------- 2) scan, pass 1 ----------
__global__ __launch_bounds__(1024) void scan1_kernel(
    const int* __restrict__ counts, int* __restrict__ starts,
    int* __restrict__ blockSum, int n)
{
    __shared__ int wsum[16];
    int t = threadIdx.x, lane = t & 63, wid = t >> 6;
    int i = blockIdx.x * 1024 + t;
    int v = (i < n) ? counts[i] : 0;
    int incl = v;
    #pragma unroll
    for (int off = 1; off < 64; off <<= 1) {
        int u = __shfl_up(incl, off);
        if (lane >= off) incl += u;
    }
    if (lane == 63) wsum[wid] = incl;
    __syncthreads();
    if (t < 16) {
        int s = wsum[t];
        #pragma unroll
        for (int off = 1; off < 16; off <<= 1) {
            int u = __shfl_up(s, off);
            if (t >= off) s += u;
        }
        wsum[t] = s;
    }
    __syncthreads();
    int woff = (wid == 0) ? 0 : wsum[wid - 1];
    if (i < n) starts[i] = woff + incl - v;
    if (t == 0) blockSum[blockIdx.x] = wsum[15];
}

// ---------- 2b) scan block sums ----------
__global__ __launch_bounds__(1024) void scan2_kernel(
    const int* __restrict__ blockSum, int* __restrict__ blockOff,
    int* __restrict__ starts, int nb, int n)
{
    __shared__ int arr[1024];
    int t = threadIdx.x;
    int v = (t < nb) ? blockSum[t] : 0;
    arr[t] = v;
    __syncthreads();
    #pragma unroll
    for (int off = 1; off < 1024; off <<= 1) {
        int x = (t >= off) ? arr[t - off] : 0;
        __syncthreads();
        arr[t] += x;
        __syncthreads();
    }
    if (t < nb) blockOff[t] = arr[t] - v;
    if (t == 0) starts[n] = arr[nb - 1];
}

// ---------- 2c) add offsets ----------
__global__ __launch_bounds__(1024) void scan3_kernel(
    int* __restrict__ starts, int* __restrict__ cursor,
    const int* __restrict__ blockOff, int n)
{
    int i = blockIdx.x * 1024 + threadIdx.x;
    if (i < n) {
        int s = starts[i] + blockOff[blockIdx.x];
        starts[i] = s;
        cursor[i] = s;
    }
}

// ---------- 3) scatter ----------
__global__ __launch_bounds__(256) void scatter_kernel(
    const float* __restrict__ R, const int* __restrict__ idx,
    int* __restrict__ cursor, float4* __restrict__ sorted, int nEdges)
{
    int e = blockIdx.x * 256 + threadIdx.x;
    if (e >= nEdges) return;
    int i = idx[e];
    int j = idx[nEdges + e];
    float rix = R[3*(size_t)i], riy = R[3*(size_t)i+1], riz = R[3*(size_t)i+2];
    float rjx = R[3*(size_t)j], rjy = R[3*(size_t)j+1], rjz = R[3*(size_t)j+2];
    float dx = rjx - rix, dy = rjy - riy, dz = rjz - riz;
    float r = sqrtf(dx*dx + dy*dy + dz*dz);
    float inv = 1.0f / (r + 1e-8f);
    int pos = atomicAdd(&cursor[i], 1);
    sorted[pos] = make_float4(r, dx*inv, dy*inv, dz*inv);
}

// ---------- 4) segmented reduce (unroll-4) ----------
__global__ __launch_bounds__(256) void accum_kernel(
    const float4* __restrict__ sorted, const int* __restrict__ starts,
    const float* __restrict__ centers, const float* __restrict__ width,
    float* __restrict__ M0M1, int nAtoms)
{
    int wv = threadIdx.x >> 6, lane = threadIdx.x & 63;
    int atom = blockIdx.x * 4 + wv;
    if (atom >= nAtoms) return;
    int s = starts[atom], e = starts[atom + 1];
    int k = lane >> 2, c = lane & 3;
    float ck = centers[k];
    float w = width[0];
    float inv2w2 = 1.0f / (2.0f * w * w);
    float acc = 0.0f;
    auto term = [&](float4 v) {
        float diff = v.x - ck;
        float b = __expf(-diff * diff * inv2w2);
        float comp = (c == 0) ? 1.0f : ((c == 1) ? v.y : ((c == 2) ? v.z : v.w));
        return b * comp;
    };
    int p = s;
    for (; p + 3 < e; p += 4) {
        float4 v0 = sorted[p];
        float4 v1 = sorted[p + 1];
        float4 v2 = sorted[p + 2];
        float4 v3 = sorted[p + 3];
        acc += term(v0); acc += term(v1); acc += term(v2); acc += term(v3);
    }
    for (; p < e; ++p) acc += term(sorted[p]);
    M0M1[(size_t)atom * 64 + lane] = acc;
}

// ---------- W -> bf16 transposed ----------
__global__ __launch_bounds__(256) void convW_kernel(
    const float* __restrict__ W, short* __restrict__ Wt, int K, int Kpad, int N)
{
    int n = blockIdx.x * 256 + threadIdx.x;
    int k = blockIdx.y;
    if (n >= N) return;
    float v = (k < K) ? W[(size_t)k * N + n] : 0.0f;
    Wt[(size_t)n * Kpad + k] = f2bf(v);
}

// ============ GEMM1 (R10 verbatim): 128x128, BK=32, 4-buf pipeline ============
__global__ __launch_bounds__(256, 2) void gemm1_mfma(
    const float* __restrict__ M0M1, const short* __restrict__ W1t,
    const float* __restrict__ bias, short* __restrict__ C, int M, int nwg)
{
    __shared__ float MsT[64][128];
    __shared__ short Asl[2][4096];
    __shared__ short Bsl[4][4096];
    int t = threadIdx.x;
    int w = t >> 6, lane = t & 63;
    int wr = w >> 1, wc = w & 1;
    int li = lane & 15, lg = lane >> 4;
    int lin = xcd_swz(blockIdx.x, nwg);
    int row0 = (lin >> 2) * 128;
    int col0 = (lin & 3) * 128;

    {
        int mrow = t >> 1, mo = (t & 1) * 32;
        int gm = row0 + mrow; if (gm > M - 1) gm = M - 1;
        const float4* src = (const float4*)(M0M1 + (size_t)gm * 64 + mo);
        #pragma unroll
        for (int q = 0; q < 8; ++q) {
            float4 v = src[q];
            int c0 = mo + q * 4;
            MsT[c0+0][mrow] = v.x; MsT[c0+1][mrow] = v.y;
            MsT[c0+2][mrow] = v.z; MsT[c0+3][mrow] = v.w;
        }
    }
    __syncthreads();

    auto stageA = [&](int kt, int buf) {
        #pragma unroll
        for (int p = 0; p < 2; ++p) {
            int cell = p * 256 + t;
            int k8 = cell >> 7, row = cell & 127;
            int kbase = kt * 32 + k8 * 8;
            bf16x8 v;
            if (kbase < 16) {
                #pragma unroll
                for (int j = 0; j < 8; ++j) v[j] = f2bf(MsT[4*(kbase+j)][row]);
            } else if (kbase < 272) {
                int g = kbase - 16, a = g >> 4, b0 = g & 15;
                float ax = MsT[4*a+1][row], ay = MsT[4*a+2][row], az = MsT[4*a+3][row];
                #pragma unroll
                for (int j = 0; j < 8; ++j) {
                    int b = b0 + j;
                    v[j] = f2bf(ax*MsT[4*b+1][row] + ay*MsT[4*b+2][row] + az*MsT[4*b+3][row]);
                }
            } else {
                #pragma unroll
                for (int j = 0; j < 8; ++j) v[j] = 0;
            }
            *(bf16x8*)&Asl[buf][cell * 8] = v;
        }
    };
    auto stageB = [&](int kt, int buf) {
        #pragma unroll
        for (int p = 0; p < 2; ++p) {
            int cell = p * 256 + t;
            int k8 = cell >> 7, col = cell & 127;
            const short* src = W1t + (size_t)(col0 + col) * K1P + kt*32 + k8*8;
            gl_lds16(src, &Bsl[buf][(p * 256 + w * 64) * 8]);
        }
    };

    f32x4 acc[4][4] = {};
    const int NS = K1P / 32;   // 9
    stageA(0, 0);
    stageB(0, 0); stageB(1, 1); stageB(2, 2);

    #pragma unroll
    for (int s = 0; s < NS; ++s) {
        if (s <= NS - 3)      asm volatile("s_waitcnt vmcnt(4) lgkmcnt(0)\n\ts_barrier" ::: "memory");
        else if (s == NS - 2) asm volatile("s_waitcnt vmcnt(2) lgkmcnt(0)\n\ts_barrier" ::: "memory");
        else                  asm volatile("s_waitcnt vmcnt(0) lgkmcnt(0)\n\ts_barrier" ::: "memory");
        if (s + 3 < NS) stageB(s + 3, (s + 3) & 3);
        bf16x8 af[4], bfr[4];
        #pragma unroll
        for (int m = 0; m < 4; ++m)
            af[m] = *(const bf16x8*)&Asl[s & 1][(lg*128 + wr*64 + m*16 + li) * 8];
        #pragma unroll
        for (int n = 0; n < 4; ++n)
            bfr[n] = *(const bf16x8*)&Bsl[s & 3][(lg*128 + wc*64 + n*16 + li) * 8];
        if (s + 1 < NS) stageA(s + 1, (s + 1) & 1);
        __builtin_amdgcn_s_setprio(1);
        #pragma unroll
        for (int m = 0; m < 4; ++m)
            #pragma unroll
            for (int n = 0; n < 4; ++n)
                acc[m][n] = __builtin_amdgcn_mfma_f32_16x16x32_bf16(af[m], bfr[n], acc[m][n], 0, 0, 0);
        __builtin_amdgcn_s_setprio(0);
    }

    float bv[4];
    #pragma unroll
    for (int n = 0; n < 4; ++n) bv[n] = bias[col0 + wc*64 + n*16 + li];
    #pragma unroll
    for (int m = 0; m < 4; ++m)
        #pragma unroll
        for (int r = 0; r < 4; ++r) {
            int row = row0 + wr*64 + m*16 + lg*4 + r;
            if (row >= M) continue;
            size_t base = (size_t)row * HID + col0 + wc*64 + li;
            #pragma unroll
            for (int n = 0; n < 4; ++n) {
                float cx = acc[m][n][r] + bv[n];
                C[base + n*16] = f2bf(silu(cx));
            }
        }
}

// ============ GEMM2: B-resident, windowed A-regs (4-slot), fused energy ============
// aw window = 16 VGPR (vs areg[16]=64 in R11/R12 which spilled at the 128 cap).
__global__ __launch_bounds__(512, 1) void gemm2_bres(
    const short* __restrict__ A, const short* __restrict__ W2t,
    const float* __restrict__ bias, const float* __restrict__ W3,
    const float* __restrict__ b3, const float* __restrict__ scale,
    const float* __restrict__ shift, const int* __restrict__ Z,
    float* __restrict__ out, int M, int T)
{
    __shared__ short Bp[8192 * 8];      // 128KB: 16 chunks x (4 k8 x 128 col) x 8 shorts
    int t = threadIdx.x;
    int w = t >> 6, lane = t & 63;
    int li = lane & 15, lg = lane >> 4;
    int lin = xcd_swz(blockIdx.x, 256);
    int col0 = (lin & 3) * 128;
    int rg = lin >> 2;

    #pragma unroll
    for (int i = 0; i < 16; ++i) {
        int cell = i * 512 + t;
        int c = cell >> 9, k8 = (cell >> 7) & 3, col = cell & 127;
        const short* src = W2t + (size_t)(col0 + col) * HID + c * 32 + k8 * 8;
        gl_lds16(src, &Bp[(i * 512 + w * 64) * 8]);
    }
    asm volatile("s_waitcnt vmcnt(0)" ::: "memory");
    __syncthreads();

    float bv[8], w3v[8];
    #pragma unroll
    for (int n = 0; n < 8; ++n) {
        int col = col0 + n * 16 + li;
        bv[n]  = bias[col];
        w3v[n] = W3[col];
    }
    float b30 = b3[0];
    float ew = 0.f;

    // A row pointer for first tile + 4-slot window prologue
    const short* arowCur;
    {
        int gr = rg * 128 + w * 16 + li; if (gr > M - 1) gr = M - 1;
        arowCur = A + (size_t)gr * HID + lg * 8;
    }
    bf16x8 aw0 = *(const bf16x8*)(arowCur +  0);
    bf16x8 aw1 = *(const bf16x8*)(arowCur + 32);
    bf16x8 aw2 = *(const bf16x8*)(arowCur + 64);
    bf16x8 aw3 = *(const bf16x8*)(arowCur + 96);

    for (int rt = rg; rt < T; rt += 64) {
        int row0w = rt * 128 + w * 16;
        // next tile's row pointer (clamped; if no next tile, reload current — values unused)
        const short* arowNext;
        {
            int rtn = (rt + 64 < T) ? rt + 64 : rt;
            int gr = rtn * 128 + w * 16 + li; if (gr > M - 1) gr = M - 1;
            arowNext = A + (size_t)gr * HID + lg * 8;
        }
        f32x4 acc[8] = {};
        #pragma unroll
        for (int kt = 0; kt < 16; ++kt) {
            bf16x8 a = (kt & 3) == 0 ? aw0 : (kt & 3) == 1 ? aw1 : (kt & 3) == 2 ? aw2 : aw3;
            bf16x8 bfr[8];
            #pragma unroll
            for (int n = 0; n < 8; ++n)
                bfr[n] = *(const bf16x8*)&Bp[((kt*4 + lg)*128 + n*16 + li) * 8];
            // refill this slot: same tile kt+4, or next tile kt-12
            bf16x8 nxt;
            if (kt < 12) nxt = *(const bf16x8*)(arowCur + (kt + 4) * 32);
            else         nxt = *(const bf16x8*)(arowNext + (kt - 12) * 32);
            #pragma unroll
            for (int n = 0; n < 8; ++n)
                acc[n] = __builtin_amdgcn_mfma_f32_16x16x32_bf16(a, bfr[n], acc[n], 0, 0, 0);
            if ((kt & 3) == 0) aw0 = nxt; else if ((kt & 3) == 1) aw1 = nxt;
            else if ((kt & 3) == 2) aw2 = nxt; else aw3 = nxt;
        }
        arowCur = arowNext;
        // fused epilogue: silu + W3 dot + scale/shift, accumulate per-wave energy
        #pragma unroll
        for (int r = 0; r < 4; ++r) {
            float s = 0.f;
            #pragma unroll
            for (int n = 0; n < 8; ++n) {
                float cx = acc[n][r] + bv[n];
                s += silu(cx) * w3v[n];
            }
            s += __shfl_xor(s, 1);
            s += __shfl_xor(s, 2);
            s += __shfl_xor(s, 4);
            s += __shfl_xor(s, 8);
            int row = row0w + lg*4 + r;
            if (li == 0 && row < M) {
                int z = Z[row];
                float e = scale[z] * s;
                if (col0 == 0) e += scale[z] * b30 + shift[z];
                ew += e;
            }
        }
    }
    #pragma unroll
    for (int off = 32; off > 0; off >>= 1) ew += __shfl_down(ew, off);
    if (lane == 0) atomicAdd(out, ew);
}

extern "C" void kernel_launch(void* const* d_in, const int* in_sizes, int n_in,
                              void* d_out, int out_size, void* d_ws, size_t ws_size,
                              hipStream_t stream)
{
    const float* R       = (const float*)d_in[0];
    const int*   Z       = (const int*)  d_in[1];
    const int*   idx     = (const int*)  d_in[2];
    const float* centers = (const float*)d_in[5];
    const float* width   = (const float*)d_in[6];
    const float* W1      = (const float*)d_in[7];
    const float* b1      = (const float*)d_in[8];
    const float* W2      = (const float*)d_in[9];
    const float* b2      = (const float*)d_in[10];
    const float* W3      = (const float*)d_in[11];
    const float* b3      = (const float*)d_in[12];
    const float* scale   = (const float*)d_in[13];
    const float* shift   = (const float*)d_in[14];

    int nAtoms = in_sizes[0] / 3;
    int nEdges = in_sizes[2] / 2;

    size_t m0m1_b = (size_t)nAtoms * 64 * sizeof(float);   // 25.6 MB
    size_t h1_b   = (size_t)nAtoms * HID * 2;              // 102.4 MB
    size_t w1t_b  = (size_t)HID * K1P * 2;                 // 288 KB
    size_t w2t_b  = (size_t)HID * HID * 2;                 // 512 KB
    if (ws_size < m0m1_b + h1_b + w1t_b + w2t_b) return;

    char* ws = (char*)d_ws;
    float* M0M1 = (float*)ws;
    char*  regB = ws + m0m1_b;
    short* h1   = (short*)regB;
    short* W1t  = (short*)(ws + m0m1_b + h1_b);
    short* W2t  = W1t + (size_t)HID * K1P;

    int nb = (nAtoms + 1023) / 1024;
    size_t sorted_b = (size_t)nEdges * sizeof(float4);
    float4* sorted = (float4*)regB;
    int* counts   = (int*)(regB + sorted_b);
    int* starts   = counts + nAtoms;
    int* cursor   = starts + nAtoms + 1;
    int* blockSum = cursor + nAtoms;
    int* blockOff = blockSum + nb;
    if (sorted_b + (size_t)(3 * nAtoms + 1 + 2 * nb) * sizeof(int) > h1_b) return;

    float* out = (float*)d_out;

    hipMemsetAsync(counts, 0, (size_t)nAtoms * sizeof(int), stream);
    hipMemsetAsync(out, 0, sizeof(float), stream);

    convW_kernel<<<dim3(2, K1P), 256, 0, stream>>>(W1, W1t, 272, K1P, HID);
    convW_kernel<<<dim3(2, HID), 256, 0, stream>>>(W2, W2t, HID, HID, HID);

    int eb = (nEdges + 255) / 256;
    hist_kernel <<<eb, 256, 0, stream>>>(idx, counts, nEdges);
    scan1_kernel<<<nb, 1024, 0, stream>>>(counts, starts, blockSum, nAtoms);
    scan2_kernel<<<1, 1024, 0, stream>>>(blockSum, blockOff, starts, nb, nAtoms);
    scan3_kernel<<<nb, 1024, 0, stream>>>(starts, cursor, blockOff, nAtoms);
    scatter_kernel<<<eb, 256, 0, stream>>>(R, idx, cursor, sorted, nEdges);
    accum_kernel<<<(nAtoms + 3) / 4, 256, 0, stream>>>(sorted, starts, centers, width, M0M1, nAtoms);

    int gb = (nAtoms + 127) / 128;   // 782 row-blocks
    int nwg = gb * 4;
    gemm1_mfma<<<nwg, 256, 0, stream>>>(M0M1, W1t, b1, h1, nAtoms, nwg);
    int T = gb;                      // 782 row-tiles
    gemm2_bres<<<256, 512, 0, stream>>>(h1, W2t, b2, W3, b3, scale, shift, Z, out, nAtoms, T);
}

// Round 14
// 523.079 us; speedup vs baseline: 1.9617x; 1.6695x over previous
//
#include <hip/hip_runtime.h>
#include <hip/hip_bf16.h>
#include <cstdint>

#define HID 512
#define K1P 288   // feat K padded 272 -> 288 (9 x BK32)

typedef __attribute__((ext_vector_type(8))) short bf16x8;
typedef __attribute__((ext_vector_type(4))) float f32x4;

__device__ __forceinline__ short f2bf(float x) {
    __hip_bfloat16 h = __float2bfloat16(x);
    return *(short*)&h;
}
__device__ __forceinline__ float silu(float x) {
    return x * (1.0f / (1.0f + __expf(-x)));
}
__device__ __forceinline__ void gl_lds16(const void* src, void* dst) {
    __builtin_amdgcn_global_load_lds(
        (const __attribute__((address_space(1))) void*)src,
        (__attribute__((address_space(3))) void*)dst, 16, 0, 0);
}
// bijective XCD swizzle (m204)
__device__ __forceinline__ int xcd_swz(int bid, int nwg) {
    int q = nwg >> 3, r = nwg & 7;
    int xcd = bid & 7, i = bid >> 3;
    int base = (xcd < r) ? xcd * (q + 1) : r * (q + 1) + (xcd - r) * q;
    return base + i;
}

// ---------- 1) histogram ----------
__global__ __launch_bounds__(256) void hist_kernel(
    const int* __restrict__ idx, int* __restrict__ counts, int nEdges)
{
    int e = blockIdx.x * 256 + threadIdx.x;
    if (e < nEdges) atomicAdd(&counts[idx[e]], 1);
}

// ---------- 2) scan, pass 1 ----------
__global__ __launch_bounds__(1024) void scan1_kernel(
    const int* __restrict__ counts, int* __restrict__ starts,
    int* __restrict__ blockSum, int n)
{
    __shared__ int wsum[16];
    int t = threadIdx.x, lane = t & 63, wid = t >> 6;
    int i = blockIdx.x * 1024 + t;
    int v = (i < n) ? counts[i] : 0;
    int incl = v;
    #pragma unroll
    for (int off = 1; off < 64; off <<= 1) {
        int u = __shfl_up(incl, off);
        if (lane >= off) incl += u;
    }
    if (lane == 63) wsum[wid] = incl;
    __syncthreads();
    if (t < 16) {
        int s = wsum[t];
        #pragma unroll
        for (int off = 1; off < 16; off <<= 1) {
            int u = __shfl_up(s, off);
            if (t >= off) s += u;
        }
        wsum[t] = s;
    }
    __syncthreads();
    int woff = (wid == 0) ? 0 : wsum[wid - 1];
    if (i < n) starts[i] = woff + incl - v;
    if (t == 0) blockSum[blockIdx.x] = wsum[15];
}

// ---------- 2b) scan block sums ----------
__global__ __launch_bounds__(1024) void scan2_kernel(
    const int* __restrict__ blockSum, int* __restrict__ blockOff,
    int* __restrict__ starts, int nb, int n)
{
    __shared__ int arr[1024];
    int t = threadIdx.x;
    int v = (t < nb) ? blockSum[t] : 0;
    arr[t] = v;
    __syncthreads();
    #pragma unroll
    for (int off = 1; off < 1024; off <<= 1) {
        int x = (t >= off) ? arr[t - off] : 0;
        __syncthreads();
        arr[t] += x;
        __syncthreads();
    }
    if (t < nb) blockOff[t] = arr[t] - v;
    if (t == 0) starts[n] = arr[nb - 1];
}

// ---------- 2c) add offsets ----------
__global__ __launch_bounds__(1024) void scan3_kernel(
    int* __restrict__ starts, int* __restrict__ cursor,
    const int* __restrict__ blockOff, int n)
{
    int i = blockIdx.x * 1024 + threadIdx.x;
    if (i < n) {
        int s = starts[i] + blockOff[blockIdx.x];
        starts[i] = s;
        cursor[i] = s;
    }
}

// ---------- 3) scatter ----------
__global__ __launch_bounds__(256) void scatter_kernel(
    const float* __restrict__ R, const int* __restrict__ idx,
    int* __restrict__ cursor, float4* __restrict__ sorted, int nEdges)
{
    int e = blockIdx.x * 256 + threadIdx.x;
    if (e >= nEdges) return;
    int i = idx[e];
    int j = idx[nEdges + e];
    float rix = R[3*(size_t)i], riy = R[3*(size_t)i+1], riz = R[3*(size_t)i+2];
    float rjx = R[3*(size_t)j], rjy = R[3*(size_t)j+1], rjz = R[3*(size_t)j+2];
    float dx = rjx - rix, dy = rjy - riy, dz = rjz - riz;
    float r = sqrtf(dx*dx + dy*dy + dz*dz);
    float inv = 1.0f / (r + 1e-8f);
    int pos = atomicAdd(&cursor[i], 1);
    sorted[pos] = make_float4(r, dx*inv, dy*inv, dz*inv);
}

// ---------- 4) segmented reduce (unroll-4) ----------
__global__ __launch_bounds__(256) void accum_kernel(
    const float4* __restrict__ sorted, const int* __restrict__ starts,
    const float* __restrict__ centers, const float* __restrict__ width,
    float* __restrict__ M0M1, int nAtoms)
{
    int wv = threadIdx.x >> 6, lane = threadIdx.x & 63;
    int atom = blockIdx.x * 4 + wv;
    if (atom >= nAtoms) return;
    int s = starts[atom], e = starts[atom + 1];
    int k = lane >> 2, c = lane & 3;
    float ck = centers[k];
    float w = width[0];
    float inv2w2 = 1.0f / (2.0f * w * w);
    float acc = 0.0f;
    auto term = [&](float4 v) {
        float diff = v.x - ck;
        float b = __expf(-diff * diff * inv2w2);
        float comp = (c == 0) ? 1.0f : ((c == 1) ? v.y : ((c == 2) ? v.z : v.w));
        return b * comp;
    };
    int p = s;
    for (; p + 3 < e; p += 4) {
        float4 v0 = sorted[p];
        float4 v1 = sorted[p + 1];
        float4 v2 = sorted[p + 2];
        float4 v3 = sorted[p + 3];
        acc += term(v0); acc += term(v1); acc += term(v2); acc += term(v3);
    }
    for (; p < e; ++p) acc += term(sorted[p]);
    M0M1[(size_t)atom * 64 + lane] = acc;
}

// ---------- W -> bf16 transposed ----------
__global__ __launch_bounds__(256) void convW_kernel(
    const float* __restrict__ W, short* __restrict__ Wt, int K, int Kpad, int N)
{
    int n = blockIdx.x * 256 + threadIdx.x;
    int k = blockIdx.y;
    if (n >= N) return;
    float v = (k < K) ? W[(size_t)k * N + n] : 0.0f;
    Wt[(size_t)n * Kpad + k] = f2bf(v);
}

// ============ GEMM1: 128x128, BK=32, 4-buf B + 3-buf A, reg-dbuf fragments ============
__global__ __launch_bounds__(256, 2) void gemm1_mfma(
    const float* __restrict__ M0M1, const short* __restrict__ W1t,
    const float* __restrict__ bias, short* __restrict__ C, int M, int nwg)
{
    __shared__ float MsT[64][128];     // 32KB
    __shared__ short Asl[3][4096];     // 3x8KB (ds_write staged feat, 2-ahead)
    __shared__ short Bsl[4][4096];     // 4x8KB (gl_lds staged, 3-ahead)
    int t = threadIdx.x;
    int w = t >> 6, lane = t & 63;
    int wr = w >> 1, wc = w & 1;
    int li = lane & 15, lg = lane >> 4;
    int lin = xcd_swz(blockIdx.x, nwg);
    int row0 = (lin >> 2) * 128;
    int col0 = (lin & 3) * 128;

    {
        int mrow = t >> 1, mo = (t & 1) * 32;
        int gm = row0 + mrow; if (gm > M - 1) gm = M - 1;
        const float4* src = (const float4*)(M0M1 + (size_t)gm * 64 + mo);
        #pragma unroll
        for (int q = 0; q < 8; ++q) {
            float4 v = src[q];
            int c0 = mo + q * 4;
            MsT[c0+0][mrow] = v.x; MsT[c0+1][mrow] = v.y;
            MsT[c0+2][mrow] = v.z; MsT[c0+3][mrow] = v.w;
        }
    }
    __syncthreads();

    auto stageA = [&](int kt, int buf) {
        #pragma unroll
        for (int p = 0; p < 2; ++p) {
            int cell = p * 256 + t;
            int k8 = cell >> 7, row = cell & 127;
            int kbase = kt * 32 + k8 * 8;
            bf16x8 v;
            if (kbase < 16) {
                #pragma unroll
                for (int j = 0; j < 8; ++j) v[j] = f2bf(MsT[4*(kbase+j)][row]);
            } else if (kbase < 272) {
                int g = kbase - 16, a = g >> 4, b0 = g & 15;
                float ax = MsT[4*a+1][row], ay = MsT[4*a+2][row], az = MsT[4*a+3][row];
                #pragma unroll
                for (int j = 0; j < 8; ++j) {
                    int b = b0 + j;
                    v[j] = f2bf(ax*MsT[4*b+1][row] + ay*MsT[4*b+2][row] + az*MsT[4*b+3][row]);
                }
            } else {
                #pragma unroll
                for (int j = 0; j < 8; ++j) v[j] = 0;
            }
            *(bf16x8*)&Asl[buf][cell * 8] = v;
        }
    };
    auto stageB = [&](int kt, int buf) {
        #pragma unroll
        for (int p = 0; p < 2; ++p) {
            int cell = p * 256 + t;
            int k8 = cell >> 7, col = cell & 127;
            const short* src = W1t + (size_t)(col0 + col) * K1P + kt*32 + k8*8;
            gl_lds16(src, &Bsl[buf][(p * 256 + w * 64) * 8]);
        }
    };

    f32x4 acc[4][4] = {};
    bf16x8 afs[2][4], bfs[2][4];
    const int NS = K1P / 32;   // 9
    stageA(0, 0); stageA(1, 1);
    stageB(0, 0); stageB(1, 1); stageB(2, 2);     // 6 B-loads in flight
    asm volatile("s_waitcnt vmcnt(4) lgkmcnt(0)\n\ts_barrier" ::: "memory");
    #pragma unroll
    for (int m = 0; m < 4; ++m)
        afs[0][m] = *(const bf16x8*)&Asl[0][(lg*128 + wr*64 + m*16 + li) * 8];
    #pragma unroll
    for (int n = 0; n < 4; ++n)
        bfs[0][n] = *(const bf16x8*)&Bsl[0][(lg*128 + wc*64 + n*16 + li) * 8];

    #pragma unroll
    for (int s = 0; s < NS; ++s) {
        if (s <= NS - 3) asm volatile("s_waitcnt vmcnt(2) lgkmcnt(0)\n\ts_barrier" ::: "memory");
        else             asm volatile("s_waitcnt vmcnt(0) lgkmcnt(0)\n\ts_barrier" ::: "memory");
        if (s + 3 < NS) stageB(s + 3, (s + 3) & 3);
        if (s + 2 < NS) stageA(s + 2, (s + 2) % 3);
        if (s + 1 < NS) {
            #pragma unroll
            for (int m = 0; m < 4; ++m)
                afs[(s+1)&1][m] = *(const bf16x8*)&Asl[(s+1) % 3][(lg*128 + wr*64 + m*16 + li) * 8];
            #pragma unroll
            for (int n = 0; n < 4; ++n)
                bfs[(s+1)&1][n] = *(const bf16x8*)&Bsl[(s+1) & 3][(lg*128 + wc*64 + n*16 + li) * 8];
        }
        __builtin_amdgcn_s_setprio(1);
        #pragma unroll
        for (int m = 0; m < 4; ++m)
            #pragma unroll
            for (int n = 0; n < 4; ++n)
                acc[m][n] = __builtin_amdgcn_mfma_f32_16x16x32_bf16(afs[s&1][m], bfs[s&1][n], acc[m][n], 0, 0, 0);
        __builtin_amdgcn_s_setprio(0);
    }

    float bv[4];
    #pragma unroll
    for (int n = 0; n < 4; ++n) bv[n] = bias[col0 + wc*64 + n*16 + li];
    #pragma unroll
    for (int m = 0; m < 4; ++m)
        #pragma unroll
        for (int r = 0; r < 4; ++r) {
            int row = row0 + wr*64 + m*16 + lg*4 + r;
            if (row >= M) continue;
            size_t base = (size_t)row * HID + col0 + wc*64 + li;
            #pragma unroll
            for (int n = 0; n < 4; ++n) {
                float cx = acc[m][n][r] + bv[n];
                C[base + n*16] = f2bf(silu(cx));
            }
        }
}

// ============ GEMM2: 128x128, BK=32, 4-buf, reg-dbuf fragments + fused energy ============
__global__ __launch_bounds__(256, 2) void gemm2_mfma(
    const short* __restrict__ A, const short* __restrict__ W2t,
    const float* __restrict__ bias, const float* __restrict__ W3,
    const float* __restrict__ b3, const float* __restrict__ scale,
    const float* __restrict__ shift, const int* __restrict__ Z,
    float* __restrict__ out, int M, int nwg)
{
    __shared__ short Asl[4][4096];     // 4x8KB
    __shared__ short Bsl[4][4096];     // 4x8KB
    __shared__ float rsum[2][128];
    __shared__ float red[4];
    int t = threadIdx.x;
    int w = t >> 6, lane = t & 63;
    int wr = w >> 1, wc = w & 1;
    int li = lane & 15, lg = lane >> 4;
    int lin = xcd_swz(blockIdx.x, nwg);
    int row0 = (lin >> 2) * 128;
    int col0 = (lin & 3) * 128;

    auto stage = [&](int kt, int buf) {
        #pragma unroll
        for (int p = 0; p < 2; ++p) {
            int cell = p * 256 + t;
            int k8 = cell >> 7, row = cell & 127;
            int gr = row0 + row; if (gr > M - 1) gr = M - 1;
            const short* src = A + (size_t)gr * HID + kt*32 + k8*8;
            gl_lds16(src, &Asl[buf][(p * 256 + w * 64) * 8]);
        }
        #pragma unroll
        for (int p = 0; p < 2; ++p) {
            int cell = p * 256 + t;
            int k8 = cell >> 7, col = cell & 127;
            const short* src = W2t + (size_t)(col0 + col) * HID + kt*32 + k8*8;
            gl_lds16(src, &Bsl[buf][(p * 256 + w * 64) * 8]);
        }
    };

    f32x4 acc[4][4] = {};
    bf16x8 afs[2][4], bfs[2][4];
    const int NS = HID / 32;   // 16
    stage(0, 0); stage(1, 1); stage(2, 2);   // 12 loads in flight
    asm volatile("s_waitcnt vmcnt(8)\n\ts_barrier" ::: "memory");
    #pragma unroll
    for (int m = 0; m < 4; ++m)
        afs[0][m] = *(const bf16x8*)&Asl[0][(lg*128 + wr*64 + m*16 + li) * 8];
    #pragma unroll
    for (int n = 0; n < 4; ++n)
        bfs[0][n] = *(const bf16x8*)&Bsl[0][(lg*128 + wc*64 + n*16 + li) * 8];

    #pragma unroll
    for (int s = 0; s < NS; ++s) {
        if (s <= NS - 3) asm volatile("s_waitcnt vmcnt(4)\n\ts_barrier" ::: "memory");
        else             asm volatile("s_waitcnt vmcnt(0)\n\ts_barrier" ::: "memory");
        if (s + 3 < NS) stage(s + 3, (s + 3) & 3);
        if (s + 1 < NS) {
            #pragma unroll
            for (int m = 0; m < 4; ++m)
                afs[(s+1)&1][m] = *(const bf16x8*)&Asl[(s+1) & 3][(lg*128 + wr*64 + m*16 + li) * 8];
            #pragma unroll
            for (int n = 0; n < 4; ++n)
                bfs[(s+1)&1][n] = *(const bf16x8*)&Bsl[(s+1) & 3][(lg*128 + wc*64 + n*16 + li) * 8];
        }
        __builtin_amdgcn_s_setprio(1);
        #pragma unroll
        for (int m = 0; m < 4; ++m)
            #pragma unroll
            for (int n = 0; n < 4; ++n)
                acc[m][n] = __builtin_amdgcn_mfma_f32_16x16x32_bf16(afs[s&1][m], bfs[s&1][n], acc[m][n], 0, 0, 0);
        __builtin_amdgcn_s_setprio(0);
    }

    // fused epilogue: silu + W3 dot + scale/shift + block energy sum
    float bv[4], w3v[4];
    #pragma unroll
    for (int n = 0; n < 4; ++n) {
        int col = col0 + wc*64 + n*16 + li;
        bv[n]  = bias[col];
        w3v[n] = W3[col];
    }
    #pragma unroll
    for (int m = 0; m < 4; ++m)
        #pragma unroll
        for (int r = 0; r < 4; ++r) {
            float s = 0.f;
            #pragma unroll
            for (int n = 0; n < 4; ++n) {
                float cx = acc[m][n][r] + bv[n];
                s += silu(cx) * w3v[n];
            }
            #pragma unroll
            for (int off = 1; off < 16; off <<= 1) s += __shfl_xor(s, off);
            if (li == 0) rsum[wc][wr*64 + m*16 + lg*4 + r] = s;
        }
    __syncthreads();
    float e = 0.f;
    if (t < 128) {
        int row = row0 + t;
        if (row < M) {
            float v = rsum[0][t] + rsum[1][t];
            int z = Z[row];
            e = scale[z] * v;
            if ((lin & 3) == 0) e += scale[z] * b3[0] + shift[z];
        }
    }
    #pragma unroll
    for (int off = 32; off > 0; off >>= 1) e += __shfl_down(e, off);
    if (lane == 0) red[w] = e;
    __syncthreads();
    if (t == 0) atomicAdd(out, red[0] + red[1] + red[2] + red[3]);
}

extern "C" void kernel_launch(void* const* d_in, const int* in_sizes, int n_in,
                              void* d_out, int out_size, void* d_ws, size_t ws_size,
                              hipStream_t stream)
{
    const float* R       = (const float*)d_in[0];
    const int*   Z       = (const int*)  d_in[1];
    const int*   idx     = (const int*)  d_in[2];
    const float* centers = (const float*)d_in[5];
    const float* width   = (const float*)d_in[6];
    const float* W1      = (const float*)d_in[7];
    const float* b1      = (const float*)d_in[8];
    const float* W2      = (const float*)d_in[9];
    const float* b2      = (const float*)d_in[10];
    const float* W3      = (const float*)d_in[11];
    const float* b3      = (const float*)d_in[12];
    const float* scale   = (const float*)d_in[13];
    const float* shift   = (const float*)d_in[14];

    int nAtoms = in_sizes[0] / 3;
    int nEdges = in_sizes[2] / 2;

    size_t m0m1_b = (size_t)nAtoms * 64 * sizeof(float);   // 25.6 MB
    size_t h1_b   = (size_t)nAtoms * HID * 2;              // 102.4 MB
    size_t w1t_b  = (size_t)HID * K1P * 2;                 // 288 KB
    size_t w2t_b  = (size_t)HID * HID * 2;                 // 512 KB
    if (ws_size < m0m1_b + h1_b + w1t_b + w2t_b) return;

    char* ws = (char*)d_ws;
    float* M0M1 = (float*)ws;
    char*  regB = ws + m0m1_b;
    short* h1   = (short*)regB;
    short* W1t  = (short*)(ws + m0m1_b + h1_b);
    short* W2t  = W1t + (size_t)HID * K1P;

    int nb = (nAtoms + 1023) / 1024;
    size_t sorted_b = (size_t)nEdges * sizeof(float4);
    float4* sorted = (float4*)regB;
    int* counts   = (int*)(regB + sorted_b);
    int* starts   = counts + nAtoms;
    int* cursor   = starts + nAtoms + 1;
    int* blockSum = cursor + nAtoms;
    int* blockOff = blockSum + nb;
    if (sorted_b + (size_t)(3 * nAtoms + 1 + 2 * nb) * sizeof(int) > h1_b) return;

    float* out = (float*)d_out;

    hipMemsetAsync(counts, 0, (size_t)nAtoms * sizeof(int), stream);
    hipMemsetAsync(out, 0, sizeof(float), stream);

    convW_kernel<<<dim3(2, K1P), 256, 0, stream>>>(W1, W1t, 272, K1P, HID);
    convW_kernel<<<dim3(2, HID), 256, 0, stream>>>(W2, W2t, HID, HID, HID);

    int eb = (nEdges + 255) / 256;
    hist_kernel <<<eb, 256, 0, stream>>>(idx, counts, nEdges);
    scan1_kernel<<<nb, 1024, 0, stream>>>(counts, starts, blockSum, nAtoms);
    scan2_kernel<<<1, 1024, 0, stream>>>(blockSum, blockOff, starts, nb, nAtoms);
    scan3_kernel<<<nb, 1024, 0, stream>>>(starts, cursor, blockOff, nAtoms);
    scatter_kernel<<<eb, 256, 0, stream>>>(R, idx, cursor, sorted, nEdges);
    accum_kernel<<<(nAtoms + 3) / 4, 256, 0, stream>>>(sorted, starts, centers, width, M0M1, nAtoms);

    int gb = (nAtoms + 127) / 128;   // 782 row-blocks
    int nwg = gb * 4;                // x4 col-blocks, col-fast in lin order
    gemm1_mfma<<<nwg, 256, 0, stream>>>(M0M1, W1t, b1, h1, nAtoms, nwg);
    gemm2_mfma<<<nwg, 256, 0, stream>>>(h1, W2t, b2, W3, b3, scale, shift, Z, out, nAtoms, nwg);
}

// Round 15
// 470.095 us; speedup vs baseline: 2.1828x; 1.1127x over previous
//
#include <hip/hip_runtime.h>
#include <hip/hip_bf16.h>
#include <cstdint>

#define HID 512
#define K1P 288   // feat K padded 272 -> 288 (9 x BK32)

typedef __attribute__((ext_vector_type(8))) short bf16x8;
typedef __attribute__((ext_vector_type(4))) float f32x4;

__device__ __forceinline__ short f2bf(float x) {
    __hip_bfloat16 h = __float2bfloat16(x);
    return *(short*)&h;
}
__device__ __forceinline__ float silu(float x) {
    return x * (1.0f / (1.0f + __expf(-x)));
}
__device__ __forceinline__ void gl_lds16(const void* src, void* dst) {
    __builtin_amdgcn_global_load_lds(
        (const __attribute__((address_space(1))) void*)src,
        (__attribute__((address_space(3))) void*)dst, 16, 0, 0);
}
// bijective XCD swizzle (m204)
__device__ __forceinline__ int xcd_swz(int bid, int nwg) {
    int q = nwg >> 3, r = nwg & 7;
    int xcd = bid & 7, i = bid >> 3;
    int base = (xcd < r) ? xcd * (q + 1) : r * (q + 1) + (xcd - r) * q;
    return base + i;
}

// ---------- 1) histogram ----------
__global__ __launch_bounds__(256) void hist_kernel(
    const int* __restrict__ idx, int* __restrict__ counts, int nEdges)
{
    int e = blockIdx.x * 256 + threadIdx.x;
    if (e < nEdges) atomicAdd(&counts[idx[e]], 1);
}

// ---------- 2) scan, pass 1 ----------
__global__ __launch_bounds__(1024) void scan1_kernel(
    const int* __restrict__ counts, int* __restrict__ starts,
    int* __restrict__ blockSum, int n)
{
    __shared__ int wsum[16];
    int t = threadIdx.x, lane = t & 63, wid = t >> 6;
    int i = blockIdx.x * 1024 + t;
    int v = (i < n) ? counts[i] : 0;
    int incl = v;
    #pragma unroll
    for (int off = 1; off < 64; off <<= 1) {
        int u = __shfl_up(incl, off);
        if (lane >= off) incl += u;
    }
    if (lane == 63) wsum[wid] = incl;
    __syncthreads();
    if (t < 16) {
        int s = wsum[t];
        #pragma unroll
        for (int off = 1; off < 16; off <<= 1) {
            int u = __shfl_up(s, off);
            if (t >= off) s += u;
        }
        wsum[t] = s;
    }
    __syncthreads();
    int woff = (wid == 0) ? 0 : wsum[wid - 1];
    if (i < n) starts[i] = woff + incl - v;
    if (t == 0) blockSum[blockIdx.x] = wsum[15];
}

// ---------- 2b) scan block sums ----------
__global__ __launch_bounds__(1024) void scan2_kernel(
    const int* __restrict__ blockSum, int* __restrict__ blockOff,
    int* __restrict__ starts, int nb, int n)
{
    __shared__ int arr[1024];
    int t = threadIdx.x;
    int v = (t < nb) ? blockSum[t] : 0;
    arr[t] = v;
    __syncthreads();
    #pragma unroll
    for (int off = 1; off < 1024; off <<= 1) {
        int x = (t >= off) ? arr[t - off] : 0;
        __syncthreads();
        arr[t] += x;
        __syncthreads();
    }
    if (t < nb) blockOff[t] = arr[t] - v;
    if (t == 0) starts[n] = arr[nb - 1];
}

// ---------- 2c) add offsets ----------
__global__ __launch_bounds__(1024) void scan3_kernel(
    int* __restrict__ starts, int* __restrict__ cursor,
    const int* __restrict__ blockOff, int n)
{
    int i = blockIdx.x * 1024 + threadIdx.x;
    if (i < n) {
        int s = starts[i] + blockOff[blockIdx.x];
        starts[i] = s;
        cursor[i] = s;
    }
}

// ---------- 3) scatter ----------
__global__ __launch_bounds__(256) void scatter_kernel(
    const float* __restrict__ R, const int* __restrict__ idx,
    int* __restrict__ cursor, float4* __restrict__ sorted, int nEdges)
{
    int e = blockIdx.x * 256 + threadIdx.x;
    if (e >= nEdges) return;
    int i = idx[e];
    int j = idx[nEdges + e];
    float rix = R[3*(size_t)i], riy = R[3*(size_t)i+1], riz = R[3*(size_t)i+2];
    float rjx = R[3*(size_t)j], rjy = R[3*(size_t)j+1], rjz = R[3*(size_t)j+2];
    float dx = rjx - rix, dy = rjy - riy, dz = rjz - riz;
    float r = sqrtf(dx*dx + dy*dy + dz*dz);
    float inv = 1.0f / (r + 1e-8f);
    int pos = atomicAdd(&cursor[i], 1);
    sorted[pos] = make_float4(r, dx*inv, dy*inv, dz*inv);
}

// ---------- 4) segmented reduce + (optional) fused feat computation ----------
__global__ __launch_bounds__(256) void accum_kernel(
    const float4* __restrict__ sorted, const int* __restrict__ starts,
    const float* __restrict__ centers, const float* __restrict__ width,
    float* __restrict__ M0M1, short* __restrict__ feat16,
    int nAtoms, int useFeat)
{
    __shared__ float sm[4][64];
    int wv = threadIdx.x >> 6, lane = threadIdx.x & 63;
    int atom = blockIdx.x * 4 + wv;
    if (atom >= nAtoms) return;
    int s = starts[atom], e = starts[atom + 1];
    int k = lane >> 2, c = lane & 3;
    float ck = centers[k];
    float w = width[0];
    float inv2w2 = 1.0f / (2.0f * w * w);
    float acc = 0.0f;
    auto term = [&](float4 v) {
        float diff = v.x - ck;
        float b = __expf(-diff * diff * inv2w2);
        float comp = (c == 0) ? 1.0f : ((c == 1) ? v.y : ((c == 2) ? v.z : v.w));
        return b * comp;
    };
    int p = s;
    for (; p + 3 < e; p += 4) {
        float4 v0 = sorted[p];
        float4 v1 = sorted[p + 1];
        float4 v2 = sorted[p + 2];
        float4 v3 = sorted[p + 3];
        acc += term(v0); acc += term(v1); acc += term(v2); acc += term(v3);
    }
    for (; p < e; ++p) acc += term(sorted[p]);

    if (!useFeat) {
        M0M1[(size_t)atom * 64 + lane] = acc;
        return;
    }
    // fused feat: share M0M1 row via wave-local LDS, emit 288 bf16 feats
    sm[wv][lane] = acc;
    asm volatile("s_waitcnt lgkmcnt(0)" ::: "memory");   // wave-local publish
    short* frow = feat16 + (size_t)atom * K1P;
    #pragma unroll
    for (int q = 0; q < 5; ++q) {
        int idx5 = q * 64 + lane;
        if (idx5 >= K1P) break;
        float val;
        if (idx5 < 16) {
            val = sm[wv][4 * idx5];                  // M0
        } else if (idx5 < 272) {
            int g = idx5 - 16, a = g >> 4, b = g & 15;
            val = sm[wv][4*a+1] * sm[wv][4*b+1]
                + sm[wv][4*a+2] * sm[wv][4*b+2]
                + sm[wv][4*a+3] * sm[wv][4*b+3];     // G1
        } else {
            val = 0.0f;                              // K pad
        }
        frow[idx5] = f2bf(val);
    }
}

// ---------- W -> bf16 transposed ----------
__global__ __launch_bounds__(256) void convW_kernel(
    const float* __restrict__ W, short* __restrict__ Wt, int K, int Kpad, int N)
{
    int n = blockIdx.x * 256 + threadIdx.x;
    int k = blockIdx.y;
    if (n >= N) return;
    float v = (k < K) ? W[(size_t)k * N + n] : 0.0f;
    Wt[(size_t)n * Kpad + k] = f2bf(v);
}

// ============ GEMM1 fallback (R10 verbatim): 128x128, BK=32, 4-buf pipeline ============
__global__ __launch_bounds__(256, 2) void gemm1_mfma(
    const float* __restrict__ M0M1, const short* __restrict__ W1t,
    const float* __restrict__ bias, short* __restrict__ C, int M, int nwg)
{
    __shared__ float MsT[64][128];
    __shared__ short Asl[2][4096];
    __shared__ short Bsl[4][4096];
    int t = threadIdx.x;
    int w = t >> 6, lane = t & 63;
    int wr = w >> 1, wc = w & 1;
    int li = lane & 15, lg = lane >> 4;
    int lin = xcd_swz(blockIdx.x, nwg);
    int row0 = (lin >> 2) * 128;
    int col0 = (lin & 3) * 128;

    {
        int mrow = t >> 1, mo = (t & 1) * 32;
        int gm = row0 + mrow; if (gm > M - 1) gm = M - 1;
        const float4* src = (const float4*)(M0M1 + (size_t)gm * 64 + mo);
        #pragma unroll
        for (int q = 0; q < 8; ++q) {
            float4 v = src[q];
            int c0 = mo + q * 4;
            MsT[c0+0][mrow] = v.x; MsT[c0+1][mrow] = v.y;
            MsT[c0+2][mrow] = v.z; MsT[c0+3][mrow] = v.w;
        }
    }
    __syncthreads();

    auto stageA = [&](int kt, int buf) {
        #pragma unroll
        for (int p = 0; p < 2; ++p) {
            int cell = p * 256 + t;
            int k8 = cell >> 7, row = cell & 127;
            int kbase = kt * 32 + k8 * 8;
            bf16x8 v;
            if (kbase < 16) {
                #pragma unroll
                for (int j = 0; j < 8; ++j) v[j] = f2bf(MsT[4*(kbase+j)][row]);
            } else if (kbase < 272) {
                int g = kbase - 16, a = g >> 4, b0 = g & 15;
                float ax = MsT[4*a+1][row], ay = MsT[4*a+2][row], az = MsT[4*a+3][row];
                #pragma unroll
                for (int j = 0; j < 8; ++j) {
                    int b = b0 + j;
                    v[j] = f2bf(ax*MsT[4*b+1][row] + ay*MsT[4*b+2][row] + az*MsT[4*b+3][row]);
                }
            } else {
                #pragma unroll
                for (int j = 0; j < 8; ++j) v[j] = 0;
            }
            *(bf16x8*)&Asl[buf][cell * 8] = v;
        }
    };
    auto stageB = [&](int kt, int buf) {
        #pragma unroll
        for (int p = 0; p < 2; ++p) {
            int cell = p * 256 + t;
            int k8 = cell >> 7, col = cell & 127;
            const short* src = W1t + (size_t)(col0 + col) * K1P + kt*32 + k8*8;
            gl_lds16(src, &Bsl[buf][(p * 256 + w * 64) * 8]);
        }
    };

    f32x4 acc[4][4] = {};
    const int NS = K1P / 32;   // 9
    stageA(0, 0);
    stageB(0, 0); stageB(1, 1); stageB(2, 2);

    #pragma unroll
    for (int s = 0; s < NS; ++s) {
        if (s <= NS - 3)      asm volatile("s_waitcnt vmcnt(4) lgkmcnt(0)\n\ts_barrier" ::: "memory");
        else if (s == NS - 2) asm volatile("s_waitcnt vmcnt(2) lgkmcnt(0)\n\ts_barrier" ::: "memory");
        else                  asm volatile("s_waitcnt vmcnt(0) lgkmcnt(0)\n\ts_barrier" ::: "memory");
        if (s + 3 < NS) stageB(s + 3, (s + 3) & 3);
        bf16x8 af[4], bfr[4];
        #pragma unroll
        for (int m = 0; m < 4; ++m)
            af[m] = *(const bf16x8*)&Asl[s & 1][(lg*128 + wr*64 + m*16 + li) * 8];
        #pragma unroll
        for (int n = 0; n < 4; ++n)
            bfr[n] = *(const bf16x8*)&Bsl[s & 3][(lg*128 + wc*64 + n*16 + li) * 8];
        if (s + 1 < NS) stageA(s + 1, (s + 1) & 1);
        __builtin_amdgcn_s_setprio(1);
        #pragma unroll
        for (int m = 0; m < 4; ++m)
            #pragma unroll
            for (int n = 0; n < 4; ++n)
                acc[m][n] = __builtin_amdgcn_mfma_f32_16x16x32_bf16(af[m], bfr[n], acc[m][n], 0, 0, 0);
        __builtin_amdgcn_s_setprio(0);
    }

    float bv[4];
    #pragma unroll
    for (int n = 0; n < 4; ++n) bv[n] = bias[col0 + wc*64 + n*16 + li];
    #pragma unroll
    for (int m = 0; m < 4; ++m)
        #pragma unroll
        for (int r = 0; r < 4; ++r) {
            int row = row0 + wr*64 + m*16 + lg*4 + r;
            if (row >= M) continue;
            size_t base = (size_t)row * HID + col0 + wc*64 + li;
            #pragma unroll
            for (int n = 0; n < 4; ++n) {
                float cx = acc[m][n][r] + bv[n];
                C[base + n*16] = f2bf(silu(cx));
            }
        }
}

// ============ GEMM1 feat-path: 128x128, BK=32, 4-buf, A from global feat ============
__global__ __launch_bounds__(256, 2) void gemm_feat(
    const short* __restrict__ F, const short* __restrict__ W1t,
    const float* __restrict__ bias, short* __restrict__ C, int M, int nwg)
{
    __shared__ short Asl[4][4096];
    __shared__ short Bsl[4][4096];
    int t = threadIdx.x;
    int w = t >> 6, lane = t & 63;
    int wr = w >> 1, wc = w & 1;
    int li = lane & 15, lg = lane >> 4;
    int lin = xcd_swz(blockIdx.x, nwg);
    int row0 = (lin >> 2) * 128;
    int col0 = (lin & 3) * 128;

    auto stage = [&](int kt, int buf) {   // 4 gl_lds per thread (2 A + 2 B)
        #pragma unroll
        for (int p = 0; p < 2; ++p) {
            int cell = p * 256 + t;
            int k8 = cell >> 7, row = cell & 127;
            int gr = row0 + row; if (gr > M - 1) gr = M - 1;
            const short* src = F + (size_t)gr * K1P + kt*32 + k8*8;
            gl_lds16(src, &Asl[buf][(p * 256 + w * 64) * 8]);
        }
        #pragma unroll
        for (int p = 0; p < 2; ++p) {
            int cell = p * 256 + t;
            int k8 = cell >> 7, col = cell & 127;
            const short* src = W1t + (size_t)(col0 + col) * K1P + kt*32 + k8*8;
            gl_lds16(src, &Bsl[buf][(p * 256 + w * 64) * 8]);
        }
    };

    f32x4 acc[4][4] = {};
    const int NS = K1P / 32;   // 9
    stage(0, 0); stage(1, 1); stage(2, 2);   // 12 loads in flight

    #pragma unroll
    for (int s = 0; s < NS; ++s) {
        if (s <= NS - 3)      asm volatile("s_waitcnt vmcnt(8)\n\ts_barrier" ::: "memory");
        else if (s == NS - 2) asm volatile("s_waitcnt vmcnt(4)\n\ts_barrier" ::: "memory");
        else                  asm volatile("s_waitcnt vmcnt(0)\n\ts_barrier" ::: "memory");
        if (s + 3 < NS) stage(s + 3, (s + 3) & 3);
        bf16x8 af[4], bfr[4];
        #pragma unroll
        for (int m = 0; m < 4; ++m)
            af[m] = *(const bf16x8*)&Asl[s & 3][(lg*128 + wr*64 + m*16 + li) * 8];
        #pragma unroll
        for (int n = 0; n < 4; ++n)
            bfr[n] = *(const bf16x8*)&Bsl[s & 3][(lg*128 + wc*64 + n*16 + li) * 8];
        __builtin_amdgcn_s_setprio(1);
        #pragma unroll
        for (int m = 0; m < 4; ++m)
            #pragma unroll
            for (int n = 0; n < 4; ++n)
                acc[m][n] = __builtin_amdgcn_mfma_f32_16x16x32_bf16(af[m], bfr[n], acc[m][n], 0, 0, 0);
        __builtin_amdgcn_s_setprio(0);
    }

    float bv[4];
    #pragma unroll
    for (int n = 0; n < 4; ++n) bv[n] = bias[col0 + wc*64 + n*16 + li];
    #pragma unroll
    for (int m = 0; m < 4; ++m)
        #pragma unroll
        for (int r = 0; r < 4; ++r) {
            int row = row0 + wr*64 + m*16 + lg*4 + r;
            if (row >= M) continue;
            size_t base = (size_t)row * HID + col0 + wc*64 + li;
            #pragma unroll
            for (int n = 0; n < 4; ++n) {
                float cx = acc[m][n][r] + bv[n];
                C[base + n*16] = f2bf(silu(cx));
            }
        }
}

// ============ GEMM2 (R10 verbatim): 128x128, BK=32, 4-buf + fused energy ============
__global__ __launch_bounds__(256, 2) void gemm2_mfma(
    const short* __restrict__ A, const short* __restrict__ W2t,
    const float* __restrict__ bias, const float* __restrict__ W3,
    const float* __restrict__ b3, const float* __restrict__ scale,
    const float* __restrict__ shift, const int* __restrict__ Z,
    float* __restrict__ out, int M, int nwg)
{
    __shared__ short Asl[4][4096];
    __shared__ short Bsl[4][4096];
    __shared__ float rsum[2][128];
    __shared__ float red[4];
    int t = threadIdx.x;
    int w = t >> 6, lane = t & 63;
    int wr = w >> 1, wc = w & 1;
    int li = lane & 15, lg = lane >> 4;
    int lin = xcd_swz(blockIdx.x, nwg);
    int row0 = (lin >> 2) * 128;
    int col0 = (lin & 3) * 128;

    auto stage = [&](int kt, int buf) {
        #pragma unroll
        for (int p = 0; p < 2; ++p) {
            int cell = p * 256 + t;
            int k8 = cell >> 7, row = cell & 127;
            int gr = row0 + row; if (gr > M - 1) gr = M - 1;
            const short* src = A + (size_t)gr * HID + kt*32 + k8*8;
            gl_lds16(src, &Asl[buf][(p * 256 + w * 64) * 8]);
        }
        #pragma unroll
        for (int p = 0; p < 2; ++p) {
            int cell = p * 256 + t;
            int k8 = cell >> 7, col = cell & 127;
            const short* src = W2t + (size_t)(col0 + col) * HID + kt*32 + k8*8;
            gl_lds16(src, &Bsl[buf][(p * 256 + w * 64) * 8]);
        }
    };

    f32x4 acc[4][4] = {};
    const int NS = HID / 32;   // 16
    stage(0, 0); stage(1, 1); stage(2, 2);

    for (int s = 0; s < NS; ++s) {
        if (s <= NS - 3)      asm volatile("s_waitcnt vmcnt(8)\n\ts_barrier" ::: "memory");
        else if (s == NS - 2) asm volatile("s_waitcnt vmcnt(4)\n\ts_barrier" ::: "memory");
        else                  asm volatile("s_waitcnt vmcnt(0)\n\ts_barrier" ::: "memory");
        if (s + 3 < NS) stage(s + 3, (s + 3) & 3);
        bf16x8 af[4], bfr[4];
        #pragma unroll
        for (int m = 0; m < 4; ++m)
            af[m] = *(const bf16x8*)&Asl[s & 3][(lg*128 + wr*64 + m*16 + li) * 8];
        #pragma unroll
        for (int n = 0; n < 4; ++n)
            bfr[n] = *(const bf16x8*)&Bsl[s & 3][(lg*128 + wc*64 + n*16 + li) * 8];
        __builtin_amdgcn_s_setprio(1);
        #pragma unroll
        for (int m = 0; m < 4; ++m)
            #pragma unroll
            for (int n = 0; n < 4; ++n)
                acc[m][n] = __builtin_amdgcn_mfma_f32_16x16x32_bf16(af[m], bfr[n], acc[m][n], 0, 0, 0);
        __builtin_amdgcn_s_setprio(0);
    }

    float bv[4], w3v[4];
    #pragma unroll
    for (int n = 0; n < 4; ++n) {
        int col = col0 + wc*64 + n*16 + li;
        bv[n]  = bias[col];
        w3v[n] = W3[col];
    }
    #pragma unroll
    for (int m = 0; m < 4; ++m)
        #pragma unroll
        for (int r = 0; r < 4; ++r) {
            float s = 0.f;
            #pragma unroll
            for (int n = 0; n < 4; ++n) {
                float cx = acc[m][n][r] + bv[n];
                s += silu(cx) * w3v[n];
            }
            #pragma unroll
            for (int off = 1; off < 16; off <<= 1) s += __shfl_xor(s, off);
            if (li == 0) rsum[wc][wr*64 + m*16 + lg*4 + r] = s;
        }
    __syncthreads();
    float e = 0.f;
    if (t < 128) {
        int row = row0 + t;
        if (row < M) {
            float v = rsum[0][t] + rsum[1][t];
            int z = Z[row];
            e = scale[z] * v;
            if ((lin & 3) == 0) e += scale[z] * b3[0] + shift[z];
        }
    }
    #pragma unroll
    for (int off = 32; off > 0; off >>= 1) e += __shfl_down(e, off);
    if (lane == 0) red[w] = e;
    __syncthreads();
    if (t == 0) atomicAdd(out, red[0] + red[1] + red[2] + red[3]);
}

extern "C" void kernel_launch(void* const* d_in, const int* in_sizes, int n_in,
                              void* d_out, int out_size, void* d_ws, size_t ws_size,
                              hipStream_t stream)
{
    const float* R       = (const float*)d_in[0];
    const int*   Z       = (const int*)  d_in[1];
    const int*   idx     = (const int*)  d_in[2];
    const float* centers = (const float*)d_in[5];
    const float* width   = (const float*)d_in[6];
    const float* W1      = (const float*)d_in[7];
    const float* b1      = (const float*)d_in[8];
    const float* W2      = (const float*)d_in[9];
    const float* b2      = (const float*)d_in[10];
    const float* W3      = (const float*)d_in[11];
    const float* b3      = (const float*)d_in[12];
    const float* scale   = (const float*)d_in[13];
    const float* shift   = (const float*)d_in[14];

    int nAtoms = in_sizes[0] / 3;
    int nEdges = in_sizes[2] / 2;

    size_t m0m1_b = (size_t)nAtoms * 64 * sizeof(float);   // 25.6 MB
    size_t h1_b   = (size_t)nAtoms * HID * 2;              // 102.4 MB
    size_t w1t_b  = (size_t)HID * K1P * 2;                 // 288 KB
    size_t w2t_b  = (size_t)HID * HID * 2;                 // 512 KB
    size_t feat_b = (size_t)nAtoms * K1P * 2;              // 57.6 MB
    if (ws_size < m0m1_b + h1_b + w1t_b + w2t_b) return;
    int useFeat = (ws_size >= m0m1_b + h1_b + w1t_b + w2t_b + feat_b) ? 1 : 0;

    char* ws = (char*)d_ws;
    float* M0M1  = (float*)ws;
    char*  regB  = ws + m0m1_b;
    short* h1    = (short*)regB;
    short* W1t   = (short*)(ws + m0m1_b + h1_b);
    short* W2t   = W1t + (size_t)HID * K1P;
    short* feat16 = (short*)(ws + m0m1_b + h1_b + w1t_b + w2t_b);

    int nb = (nAtoms + 1023) / 1024;
    size_t sorted_b = (size_t)nEdges * sizeof(float4);
    float4* sorted = (float4*)regB;
    int* counts   = (int*)(regB + sorted_b);
    int* starts   = counts + nAtoms;
    int* cursor   = starts + nAtoms + 1;
    int* blockSum = cursor + nAtoms;
    int* blockOff = blockSum + nb;
    if (sorted_b + (size_t)(3 * nAtoms + 1 + 2 * nb) * sizeof(int) > h1_b) return;

    float* out = (float*)d_out;

    hipMemsetAsync(counts, 0, (size_t)nAtoms * sizeof(int), stream);
    hipMemsetAsync(out, 0, sizeof(float), stream);

    convW_kernel<<<dim3(2, K1P), 256, 0, stream>>>(W1, W1t, 272, K1P, HID);
    convW_kernel<<<dim3(2, HID), 256, 0, stream>>>(W2, W2t, HID, HID, HID);

    int eb = (nEdges + 255) / 256;
    hist_kernel <<<eb, 256, 0, stream>>>(idx, counts, nEdges);
    scan1_kernel<<<nb, 1024, 0, stream>>>(counts, starts, blockSum, nAtoms);
    scan2_kernel<<<1, 1024, 0, stream>>>(blockSum, blockOff, starts, nb, nAtoms);
    scan3_kernel<<<nb, 1024, 0, stream>>>(starts, cursor, blockOff, nAtoms);
    scatter_kernel<<<eb, 256, 0, stream>>>(R, idx, cursor, sorted, nEdges);
    accum_kernel<<<(nAtoms + 3) / 4, 256, 0, stream>>>(sorted, starts, centers, width,
                                                       M0M1, feat16, nAtoms, useFeat);

    int gb = (nAtoms + 127) / 128;   // 782 row-blocks
    int nwg = gb * 4;                // x4 col-blocks, col-fast in lin order
    if (useFeat)
        gemm_feat<<<nwg, 256, 0, stream>>>(feat16, W1t, b1, h1, nAtoms, nwg);
    else
        gemm1_mfma<<<nwg, 256, 0, stream>>>(M0M1, W1t, b1, h1, nAtoms, nwg);
    gemm2_mfma<<<nwg, 256, 0, stream>>>(h1, W2t, b2, W3, b3, scale, shift, Z, out, nAtoms, nwg);
}

// Round 16
// 435.913 us; speedup vs baseline: 2.3540x; 1.0784x over previous
//
#include <hip/hip_runtime.h>
#include <hip/hip_bf16.h>
#include <cstdint>

#define HID 512
#define K1P 288   // feat K padded 272 -> 288 (9 x BK32)

typedef __attribute__((ext_vector_type(8))) short bf16x8;
typedef __attribute__((ext_vector_type(4))) float f32x4;

__device__ __forceinline__ short f2bf(float x) {
    __hip_bfloat16 h = __float2bfloat16(x);
    return *(short*)&h;
}
__device__ __forceinline__ float silu(float x) {
    return x * (1.0f / (1.0f + __expf(-x)));
}
__device__ __forceinline__ void gl_lds16(const void* src, void* dst) {
    __builtin_amdgcn_global_load_lds(
        (const __attribute__((address_space(1))) void*)src,
        (__attribute__((address_space(3))) void*)dst, 16, 0, 0);
}
// bijective XCD swizzle (m204)
__device__ __forceinline__ int xcd_swz(int bid, int nwg) {
    int q = nwg >> 3, r = nwg & 7;
    int xcd = bid & 7, i = bid >> 3;
    int base = (xcd < r) ? xcd * (q + 1) : r * (q + 1) + (xcd - r) * q;
    return base + i;
}

// ---------- 1) histogram ----------
__global__ __launch_bounds__(256) void hist_kernel(
    const int* __restrict__ idx, int* __restrict__ counts, int nEdges)
{
    int e = blockIdx.x * 256 + threadIdx.x;
    if (e < nEdges) atomicAdd(&counts[idx[e]], 1);
}

// ---------- 2) scan, pass 1 ----------
__global__ __launch_bounds__(1024) void scan1_kernel(
    const int* __restrict__ counts, int* __restrict__ starts,
    int* __restrict__ blockSum, int n)
{
    __shared__ int wsum[16];
    int t = threadIdx.x, lane = t & 63, wid = t >> 6;
    int i = blockIdx.x * 1024 + t;
    int v = (i < n) ? counts[i] : 0;
    int incl = v;
    #pragma unroll
    for (int off = 1; off < 64; off <<= 1) {
        int u = __shfl_up(incl, off);
        if (lane >= off) incl += u;
    }
    if (lane == 63) wsum[wid] = incl;
    __syncthreads();
    if (t < 16) {
        int s = wsum[t];
        #pragma unroll
        for (int off = 1; off < 16; off <<= 1) {
            int u = __shfl_up(s, off);
            if (t >= off) s += u;
        }
        wsum[t] = s;
    }
    __syncthreads();
    int woff = (wid == 0) ? 0 : wsum[wid - 1];
    if (i < n) starts[i] = woff + incl - v;
    if (t == 0) blockSum[blockIdx.x] = wsum[15];
}

// ---------- 2b) scan block sums ----------
__global__ __launch_bounds__(1024) void scan2_kernel(
    const int* __restrict__ blockSum, int* __restrict__ blockOff,
    int* __restrict__ starts, int nb, int n)
{
    __shared__ int arr[1024];
    int t = threadIdx.x;
    int v = (t < nb) ? blockSum[t] : 0;
    arr[t] = v;
    __syncthreads();
    #pragma unroll
    for (int off = 1; off < 1024; off <<= 1) {
        int x = (t >= off) ? arr[t - off] : 0;
        __syncthreads();
        arr[t] += x;
        __syncthreads();
    }
    if (t < nb) blockOff[t] = arr[t] - v;
    if (t == 0) starts[n] = arr[nb - 1];
}

// ---------- 2c) add offsets ----------
__global__ __launch_bounds__(1024) void scan3_kernel(
    int* __restrict__ starts, int* __restrict__ cursor,
    const int* __restrict__ blockOff, int n)
{
    int i = blockIdx.x * 1024 + threadIdx.x;
    if (i < n) {
        int s = starts[i] + blockOff[blockIdx.x];
        starts[i] = s;
        cursor[i] = s;
    }
}

// ---------- 3) scatter ----------
__global__ __launch_bounds__(256) void scatter_kernel(
    const float* __restrict__ R, const int* __restrict__ idx,
    int* __restrict__ cursor, float4* __restrict__ sorted, int nEdges)
{
    int e = blockIdx.x * 256 + threadIdx.x;
    if (e >= nEdges) return;
    int i = idx[e];
    int j = idx[nEdges + e];
    float rix = R[3*(size_t)i], riy = R[3*(size_t)i+1], riz = R[3*(size_t)i+2];
    float rjx = R[3*(size_t)j], rjy = R[3*(size_t)j+1], rjz = R[3*(size_t)j+2];
    float dx = rjx - rix, dy = rjy - riy, dz = rjz - riz;
    float r = sqrtf(dx*dx + dy*dy + dz*dz);
    float inv = 1.0f / (r + 1e-8f);
    int pos = atomicAdd(&cursor[i], 1);
    sorted[pos] = make_float4(r, dx*inv, dy*inv, dz*inv);
}

// ---------- 4) segmented reduce + fused feat computation ----------
__global__ __launch_bounds__(256) void accum_kernel(
    const float4* __restrict__ sorted, const int* __restrict__ starts,
    const float* __restrict__ centers, const float* __restrict__ width,
    float* __restrict__ M0M1, short* __restrict__ feat16,
    int nAtoms, int useFeat)
{
    __shared__ float sm[4][64];
    int wv = threadIdx.x >> 6, lane = threadIdx.x & 63;
    int atom = blockIdx.x * 4 + wv;
    if (atom >= nAtoms) return;
    int s = starts[atom], e = starts[atom + 1];
    int k = lane >> 2, c = lane & 3;
    float ck = centers[k];
    float w = width[0];
    float inv2w2 = 1.0f / (2.0f * w * w);
    float acc = 0.0f;
    auto term = [&](float4 v) {
        float diff = v.x - ck;
        float b = __expf(-diff * diff * inv2w2);
        float comp = (c == 0) ? 1.0f : ((c == 1) ? v.y : ((c == 2) ? v.z : v.w));
        return b * comp;
    };
    int p = s;
    for (; p + 3 < e; p += 4) {
        float4 v0 = sorted[p];
        float4 v1 = sorted[p + 1];
        float4 v2 = sorted[p + 2];
        float4 v3 = sorted[p + 3];
        acc += term(v0); acc += term(v1); acc += term(v2); acc += term(v3);
    }
    for (; p < e; ++p) acc += term(sorted[p]);

    if (!useFeat) {
        M0M1[(size_t)atom * 64 + lane] = acc;
        return;
    }
    sm[wv][lane] = acc;
    asm volatile("s_waitcnt lgkmcnt(0)" ::: "memory");   // wave-local publish
    short* frow = feat16 + (size_t)atom * K1P;
    #pragma unroll
    for (int q = 0; q < 5; ++q) {
        int idx5 = q * 64 + lane;
        if (idx5 >= K1P) break;
        float val;
        if (idx5 < 16) {
            val = sm[wv][4 * idx5];
        } else if (idx5 < 272) {
            int g = idx5 - 16, a = g >> 4, b = g & 15;
            val = sm[wv][4*a+1] * sm[wv][4*b+1]
                + sm[wv][4*a+2] * sm[wv][4*b+2]
                + sm[wv][4*a+3] * sm[wv][4*b+3];
        } else {
            val = 0.0f;
        }
        frow[idx5] = f2bf(val);
    }
}

// ---------- W -> bf16 transposed ----------
__global__ __launch_bounds__(256) void convW_kernel(
    const float* __restrict__ W, short* __restrict__ Wt, int K, int Kpad, int N)
{
    int n = blockIdx.x * 256 + threadIdx.x;
    int k = blockIdx.y;
    if (n >= N) return;
    float v = (k < K) ? W[(size_t)k * N + n] : 0.0f;
    Wt[(size_t)n * Kpad + k] = f2bf(v);
}

// ============ GEMM1 fallback (R10 verbatim): 128x128, BK=32, 4-buf pipeline ============
__global__ __launch_bounds__(256, 2) void gemm1_mfma(
    const float* __restrict__ M0M1, const short* __restrict__ W1t,
    const float* __restrict__ bias, short* __restrict__ C, int M, int nwg)
{
    __shared__ float MsT[64][128];
    __shared__ short Asl[2][4096];
    __shared__ short Bsl[4][4096];
    int t = threadIdx.x;
    int w = t >> 6, lane = t & 63;
    int wr = w >> 1, wc = w & 1;
    int li = lane & 15, lg = lane >> 4;
    int lin = xcd_swz(blockIdx.x, nwg);
    int row0 = (lin >> 2) * 128;
    int col0 = (lin & 3) * 128;

    {
        int mrow = t >> 1, mo = (t & 1) * 32;
        int gm = row0 + mrow; if (gm > M - 1) gm = M - 1;
        const float4* src = (const float4*)(M0M1 + (size_t)gm * 64 + mo);
        #pragma unroll
        for (int q = 0; q < 8; ++q) {
            float4 v = src[q];
            int c0 = mo + q * 4;
            MsT[c0+0][mrow] = v.x; MsT[c0+1][mrow] = v.y;
            MsT[c0+2][mrow] = v.z; MsT[c0+3][mrow] = v.w;
        }
    }
    __syncthreads();

    auto stageA = [&](int kt, int buf) {
        #pragma unroll
        for (int p = 0; p < 2; ++p) {
            int cell = p * 256 + t;
            int k8 = cell >> 7, row = cell & 127;
            int kbase = kt * 32 + k8 * 8;
            bf16x8 v;
            if (kbase < 16) {
                #pragma unroll
                for (int j = 0; j < 8; ++j) v[j] = f2bf(MsT[4*(kbase+j)][row]);
            } else if (kbase < 272) {
                int g = kbase - 16, a = g >> 4, b0 = g & 15;
                float ax = MsT[4*a+1][row], ay = MsT[4*a+2][row], az = MsT[4*a+3][row];
                #pragma unroll
                for (int j = 0; j < 8; ++j) {
                    int b = b0 + j;
                    v[j] = f2bf(ax*MsT[4*b+1][row] + ay*MsT[4*b+2][row] + az*MsT[4*b+3][row]);
                }
            } else {
                #pragma unroll
                for (int j = 0; j < 8; ++j) v[j] = 0;
            }
            *(bf16x8*)&Asl[buf][cell * 8] = v;
        }
    };
    auto stageB = [&](int kt, int buf) {
        #pragma unroll
        for (int p = 0; p < 2; ++p) {
            int cell = p * 256 + t;
            int k8 = cell >> 7, col = cell & 127;
            const short* src = W1t + (size_t)(col0 + col) * K1P + kt*32 + k8*8;
            gl_lds16(src, &Bsl[buf][(p * 256 + w * 64) * 8]);
        }
    };

    f32x4 acc[4][4] = {};
    const int NS = K1P / 32;   // 9
    stageA(0, 0);
    stageB(0, 0); stageB(1, 1); stageB(2, 2);

    #pragma unroll
    for (int s = 0; s < NS; ++s) {
        if (s <= NS - 3)      asm volatile("s_waitcnt vmcnt(4) lgkmcnt(0)\n\ts_barrier" ::: "memory");
        else if (s == NS - 2) asm volatile("s_waitcnt vmcnt(2) lgkmcnt(0)\n\ts_barrier" ::: "memory");
        else                  asm volatile("s_waitcnt vmcnt(0) lgkmcnt(0)\n\ts_barrier" ::: "memory");
        if (s + 3 < NS) stageB(s + 3, (s + 3) & 3);
        bf16x8 af[4], bfr[4];
        #pragma unroll
        for (int m = 0; m < 4; ++m)
            af[m] = *(const bf16x8*)&Asl[s & 1][(lg*128 + wr*64 + m*16 + li) * 8];
        #pragma unroll
        for (int n = 0; n < 4; ++n)
            bfr[n] = *(const bf16x8*)&Bsl[s & 3][(lg*128 + wc*64 + n*16 + li) * 8];
        if (s + 1 < NS) stageA(s + 1, (s + 1) & 1);
        __builtin_amdgcn_s_setprio(1);
        #pragma unroll
        for (int m = 0; m < 4; ++m)
            #pragma unroll
            for (int n = 0; n < 4; ++n)
                acc[m][n] = __builtin_amdgcn_mfma_f32_16x16x32_bf16(af[m], bfr[n], acc[m][n], 0, 0, 0);
        __builtin_amdgcn_s_setprio(0);
    }

    float bv[4];
    #pragma unroll
    for (int n = 0; n < 4; ++n) bv[n] = bias[col0 + wc*64 + n*16 + li];
    #pragma unroll
    for (int m = 0; m < 4; ++m)
        #pragma unroll
        for (int r = 0; r < 4; ++r) {
            int row = row0 + wr*64 + m*16 + lg*4 + r;
            if (row >= M) continue;
            size_t base = (size_t)row * HID + col0 + wc*64 + li;
            #pragma unroll
            for (int n = 0; n < 4; ++n) {
                float cx = acc[m][n][r] + bv[n];
                C[base + n*16] = f2bf(silu(cx));
            }
        }
}

// ============ GEMM1 feat-path: 128x128, BK=32, 3-buf/1-ahead, hoisted addrs ============
__global__ __launch_bounds__(256, 3) void gemm_feat(
    const short* __restrict__ F, const short* __restrict__ W1t,
    const float* __restrict__ bias, short* __restrict__ C, int M, int nwg)
{
    __shared__ short Asl[3][4096];   // 3x8KB
    __shared__ short Bsl[3][4096];   // 3x8KB -> total 48KB: 3 blocks/CU
    int t = threadIdx.x;
    int w = t >> 6, lane = t & 63;
    int wr = w >> 1, wc = w & 1;
    int li = lane & 15, lg = lane >> 4;
    int lin = xcd_swz(blockIdx.x, nwg);
    int row0 = (lin >> 2) * 128;
    int col0 = (lin & 3) * 128;

    // hoisted per-thread source addresses (advance by kt*32 shorts per step)
    int rr = t & 127, k8h = t >> 7;
    int grA = row0 + rr; if (grA > M - 1) grA = M - 1;
    const short* aSrc0 = F + (size_t)grA * K1P + k8h * 8;
    const short* aSrc1 = aSrc0 + 16;
    const short* bSrc0 = W1t + (size_t)(col0 + rr) * K1P + k8h * 8;
    const short* bSrc1 = bSrc0 + 16;

    auto stage = [&](int kt, int buf) {
        gl_lds16(aSrc0 + kt * 32, &Asl[buf][(w * 64) * 8]);
        gl_lds16(aSrc1 + kt * 32, &Asl[buf][(256 + w * 64) * 8]);
        gl_lds16(bSrc0 + kt * 32, &Bsl[buf][(w * 64) * 8]);
        gl_lds16(bSrc1 + kt * 32, &Bsl[buf][(256 + w * 64) * 8]);
    };

    f32x4 acc[4][4] = {};
    const int NS = K1P / 32;   // 9
    stage(0, 0); stage(1, 1);  // 8 loads in flight

    #pragma unroll
    for (int s = 0; s < NS; ++s) {
        if (s < NS - 1) asm volatile("s_waitcnt vmcnt(4)\n\ts_barrier" ::: "memory");
        else            asm volatile("s_waitcnt vmcnt(0)\n\ts_barrier" ::: "memory");
        if (s + 2 < NS) stage(s + 2, (s + 2) % 3);
        bf16x8 af[4], bfr[4];
        #pragma unroll
        for (int m = 0; m < 4; ++m)
            af[m] = *(const bf16x8*)&Asl[s % 3][(lg*128 + wr*64 + m*16 + li) * 8];
        #pragma unroll
        for (int n = 0; n < 4; ++n)
            bfr[n] = *(const bf16x8*)&Bsl[s % 3][(lg*128 + wc*64 + n*16 + li) * 8];
        __builtin_amdgcn_s_setprio(1);
        #pragma unroll
        for (int m = 0; m < 4; ++m)
            #pragma unroll
            for (int n = 0; n < 4; ++n)
                acc[m][n] = __builtin_amdgcn_mfma_f32_16x16x32_bf16(af[m], bfr[n], acc[m][n], 0, 0, 0);
        __builtin_amdgcn_s_setprio(0);
    }

    float bv[4];
    #pragma unroll
    for (int n = 0; n < 4; ++n) bv[n] = bias[col0 + wc*64 + n*16 + li];
    #pragma unroll
    for (int m = 0; m < 4; ++m)
        #pragma unroll
        for (int r = 0; r < 4; ++r) {
            int row = row0 + wr*64 + m*16 + lg*4 + r;
            if (row >= M) continue;
            size_t base = (size_t)row * HID + col0 + wc*64 + li;
            #pragma unroll
            for (int n = 0; n < 4; ++n) {
                float cx = acc[m][n][r] + bv[n];
                C[base + n*16] = f2bf(silu(cx));
            }
        }
}

// ============ GEMM2: 128x128, BK=32, 3-buf/1-ahead, hoisted addrs + fused energy ============
__global__ __launch_bounds__(256, 3) void gemm2_mfma(
    const short* __restrict__ A, const short* __restrict__ W2t,
    const float* __restrict__ bias, const float* __restrict__ W3,
    const float* __restrict__ b3, const float* __restrict__ scale,
    const float* __restrict__ shift, const int* __restrict__ Z,
    float* __restrict__ out, int M, int nwg)
{
    __shared__ short Asl[3][4096];   // 3x8KB
    __shared__ short Bsl[3][4096];   // 3x8KB
    __shared__ float rsum[2][128];
    __shared__ float red[4];         // total ~49.3KB: 3 blocks/CU
    int t = threadIdx.x;
    int w = t >> 6, lane = t & 63;
    int wr = w >> 1, wc = w & 1;
    int li = lane & 15, lg = lane >> 4;
    int lin = xcd_swz(blockIdx.x, nwg);
    int row0 = (lin >> 2) * 128;
    int col0 = (lin & 3) * 128;

    int rr = t & 127, k8h = t >> 7;
    int grA = row0 + rr; if (grA > M - 1) grA = M - 1;
    const short* aSrc0 = A + (size_t)grA * HID + k8h * 8;
    const short* aSrc1 = aSrc0 + 16;
    const short* bSrc0 = W2t + (size_t)(col0 + rr) * HID + k8h * 8;
    const short* bSrc1 = bSrc0 + 16;

    auto stage = [&](int kt, int buf) {
        gl_lds16(aSrc0 + kt * 32, &Asl[buf][(w * 64) * 8]);
        gl_lds16(aSrc1 + kt * 32, &Asl[buf][(256 + w * 64) * 8]);
        gl_lds16(bSrc0 + kt * 32, &Bsl[buf][(w * 64) * 8]);
        gl_lds16(bSrc1 + kt * 32, &Bsl[buf][(256 + w * 64) * 8]);
    };

    f32x4 acc[4][4] = {};
    const int NS = HID / 32;   // 16
    stage(0, 0); stage(1, 1);  // 8 loads in flight

    for (int s = 0; s < NS; ++s) {
        if (s < NS - 1) asm volatile("s_waitcnt vmcnt(4)\n\ts_barrier" ::: "memory");
        else            asm volatile("s_waitcnt vmcnt(0)\n\ts_barrier" ::: "memory");
        if (s + 2 < NS) stage(s + 2, (s + 2) % 3);
        bf16x8 af[4], bfr[4];
        #pragma unroll
        for (int m = 0; m < 4; ++m)
            af[m] = *(const bf16x8*)&Asl[s % 3][(lg*128 + wr*64 + m*16 + li) * 8];
        #pragma unroll
        for (int n = 0; n < 4; ++n)
            bfr[n] = *(const bf16x8*)&Bsl[s % 3][(lg*128 + wc*64 + n*16 + li) * 8];
        __builtin_amdgcn_s_setprio(1);
        #pragma unroll
        for (int m = 0; m < 4; ++m)
            #pragma unroll
            for (int n = 0; n < 4; ++n)
                acc[m][n] = __builtin_amdgcn_mfma_f32_16x16x32_bf16(af[m], bfr[n], acc[m][n], 0, 0, 0);
        __builtin_amdgcn_s_setprio(0);
    }

    float bv[4], w3v[4];
    #pragma unroll
    for (int n = 0; n < 4; ++n) {
        int col = col0 + wc*64 + n*16 + li;
        bv[n]  = bias[col];
        w3v[n] = W3[col];
    }
    #pragma unroll
    for (int m = 0; m < 4; ++m)
        #pragma unroll
        for (int r = 0; r < 4; ++r) {
            float s = 0.f;
            #pragma unroll
            for (int n = 0; n < 4; ++n) {
                float cx = acc[m][n][r] + bv[n];
                s += silu(cx) * w3v[n];
            }
            #pragma unroll
            for (int off = 1; off < 16; off <<= 1) s += __shfl_xor(s, off);
            if (li == 0) rsum[wc][wr*64 + m*16 + lg*4 + r] = s;
        }
    __syncthreads();
    float e = 0.f;
    if (t < 128) {
        int row = row0 + t;
        if (row < M) {
            float v = rsum[0][t] + rsum[1][t];
            int z = Z[row];
            e = scale[z] * v;
            if ((lin & 3) == 0) e += scale[z] * b3[0] + shift[z];
        }
    }
    #pragma unroll
    for (int off = 32; off > 0; off >>= 1) e += __shfl_down(e, off);
    if (lane == 0) red[w] = e;
    __syncthreads();
    if (t == 0) atomicAdd(out, red[0] + red[1] + red[2] + red[3]);
}

extern "C" void kernel_launch(void* const* d_in, const int* in_sizes, int n_in,
                              void* d_out, int out_size, void* d_ws, size_t ws_size,
                              hipStream_t stream)
{
    const float* R       = (const float*)d_in[0];
    const int*   Z       = (const int*)  d_in[1];
    const int*   idx     = (const int*)  d_in[2];
    const float* centers = (const float*)d_in[5];
    const float* width   = (const float*)d_in[6];
    const float* W1      = (const float*)d_in[7];
    const float* b1      = (const float*)d_in[8];
    const float* W2      = (const float*)d_in[9];
    const float* b2      = (const float*)d_in[10];
    const float* W3      = (const float*)d_in[11];
    const float* b3      = (const float*)d_in[12];
    const float* scale   = (const float*)d_in[13];
    const float* shift   = (const float*)d_in[14];

    int nAtoms = in_sizes[0] / 3;
    int nEdges = in_sizes[2] / 2;

    size_t m0m1_b = (size_t)nAtoms * 64 * sizeof(float);   // 25.6 MB
    size_t h1_b   = (size_t)nAtoms * HID * 2;              // 102.4 MB
    size_t w1t_b  = (size_t)HID * K1P * 2;                 // 288 KB
    size_t w2t_b  = (size_t)HID * HID * 2;                 // 512 KB
    size_t feat_b = (size_t)nAtoms * K1P * 2;              // 57.6 MB
    if (ws_size < m0m1_b + h1_b + w1t_b + w2t_b) return;
    int useFeat = (ws_size >= m0m1_b + h1_b + w1t_b + w2t_b + feat_b) ? 1 : 0;

    char* ws = (char*)d_ws;
    float* M0M1  = (float*)ws;
    char*  regB  = ws + m0m1_b;
    short* h1    = (short*)regB;
    short* W1t   = (short*)(ws + m0m1_b + h1_b);
    short* W2t   = W1t + (size_t)HID * K1P;
    short* feat16 = (short*)(ws + m0m1_b + h1_b + w1t_b + w2t_b);

    int nb = (nAtoms + 1023) / 1024;
    size_t sorted_b = (size_t)nEdges * sizeof(float4);
    float4* sorted = (float4*)regB;
    int* counts   = (int*)(regB + sorted_b);
    int* starts   = counts + nAtoms;
    int* cursor   = starts + nAtoms + 1;
    int* blockSum = cursor + nAtoms;
    int* blockOff = blockSum + nb;
    if (sorted_b + (size_t)(3 * nAtoms + 1 + 2 * nb) * sizeof(int) > h1_b) return;

    float* out = (float*)d_out;

    hipMemsetAsync(counts, 0, (size_t)nAtoms * sizeof(int), stream);
    hipMemsetAsync(out, 0, sizeof(float), stream);

    convW_kernel<<<dim3(2, K1P), 256, 0, stream>>>(W1, W1t, 272, K1P, HID);
    convW_kernel<<<dim3(2, HID), 256, 0, stream>>>(W2, W2t, HID, HID, HID);

    int eb = (nEdges + 255) / 256;
    hist_kernel <<<eb, 256, 0, stream>>>(idx, counts, nEdges);
    scan1_kernel<<<nb, 1024, 0, stream>>>(counts, starts, blockSum, nAtoms);
    scan2_kernel<<<1, 1024, 0, stream>>>(blockSum, blockOff, starts, nb, nAtoms);
    scan3_kernel<<<nb, 1024, 0, stream>>>(starts, cursor, blockOff, nAtoms);
    scatter_kernel<<<eb, 256, 0, stream>>>(R, idx, cursor, sorted, nEdges);
    accum_kernel<<<(nAtoms + 3) / 4, 256, 0, stream>>>(sorted, starts, centers, width,
                                                       M0M1, feat16, nAtoms, useFeat);

    int gb = (nAtoms + 127) / 128;   // 782 row-blocks
    int nwg = gb * 4;                // x4 col-blocks, col-fast in lin order
    if (useFeat)
        gemm_feat<<<nwg, 256, 0, stream>>>(feat16, W1t, b1, h1, nAtoms, nwg);
    else
        gemm1_mfma<<<nwg, 256, 0, stream>>>(M0M1, W1t, b1, h1, nAtoms, nwg);
    gemm2_mfma<<<nwg, 256, 0, stream>>>(h1, W2t, b2, W3, b3, scale, shift, Z, out, nAtoms, nwg);
}